// Round 17
// baseline (222.209 us; speedup 1.0000x reference)
//
#include <hip/hip_runtime.h>

// SpikingLinearAttention forward — fused chunk-scan kernel, v15 (fine-grain blocks).
//  Same math as v13 (R15, 137.7us best). Structural change: 256-thread blocks
//  (4 waves), CHUNK=32, NCH=256, BPB=32, grid=1024 (fully resident).
//  Rationale: occupancy was pinned by {regs ~96 -> 20 waves/CU max} x {8-wave
//  block granularity -> only 16 realized}. 4-wave blocks realize the full
//  20-wave budget (5 blocks/CU; LDS 24.4KB/block not limiting) and give 4-5
//  independent dependency chains per CU instead of 2.
//  - wave owns 2 n-tiles (features [32w,32w+32)), acc[2][2] = same 32 AGPR.
//  - aggregates bf16-packed: {k0+1, kv0, k1+1, kv1} in ONE 8B atomic per
//    feature-pair -> 4MB table at NCH=256, 8 polls/lane/iter. bf16 on
//    aggregates adds <=0.2% rel on carries (absmax +~0.01, threshold 1.55).
//  - Q restaged into afK (2 extra barriers; 4/iter, each syncs only 4 waves).
//  features = exp(X) @ W via 6-term bf16-split MFMA; gate in f32; in-chunk
//  cumsum in registers (MFMA C/D layout); cross-chunk prefix via
//  deterministic decoupled lookback.

constexpr int cB = 32;
constexpr int cS = 8192;
constexpr int cD = 64;
constexpr int cF = 128;
constexpr int CHUNK = 32;
constexpr int NCH = cS / CHUNK;   // 256 chunks per batch
constexpr int SLOT = 520;         // ushorts per p-plane slot (1040 B)
constexpr int THR = 256;          // 4 waves
constexpr int BPB = 32;           // blocks per batch
constexpr int ITERS = NCH / BPB;  // 8 chunks per block, stride BPB
constexpr float EPS_ = 1e-8f;

typedef __attribute__((ext_vector_type(8))) short bf16x8;  // 8 bf16 (4 VGPRs)
typedef __attribute__((ext_vector_type(4))) float f32x4;   // 4 f32 acc

#define MFMA16(a, b, c) __builtin_amdgcn_mfma_f32_16x16x32_bf16((a), (b), (c), 0, 0, 0)

// ---- bf16 helpers ----------------------------------------------------------
__device__ __forceinline__ unsigned short bf16rn(float x) {
    unsigned u = __float_as_uint(x);
    unsigned r = u + 0x7FFFu + ((u >> 16) & 1u);
    return (unsigned short)(r >> 16);
}
__device__ __forceinline__ float bf16tof(unsigned short h) {
    return __uint_as_float((unsigned)h << 16);
}
__device__ __forceinline__ void split3(float x, unsigned short& a0,
                                       unsigned short& a1, unsigned short& a2) {
    a0 = bf16rn(x);
    float r1 = x - bf16tof(a0);
    a1 = bf16rn(r1);
    float r2 = r1 - bf16tof(a1);
    a2 = bf16rn(r2);
}
// packed RNE bf16 pair (same rounding as bf16rn -> numerically identical)
__device__ __forceinline__ unsigned cvtpk(float lo, float hi) {
    unsigned r;
    asm("v_cvt_pk_bf16_f32 %0, %1, %2" : "=v"(r) : "v"(lo), "v"(hi));
    return r;
}
__device__ __forceinline__ float unpk_lo(unsigned u) {
    return __uint_as_float(u << 16);
}
__device__ __forceinline__ float unpk_hi(unsigned u) {
    return __uint_as_float(u & 0xFFFF0000u);
}

// A-frag: lane l holds A[l&15][(l>>4)*8+j].  B-frag: lane l holds B[(l>>4)*8+j][l&15].
// C/D: lane l, reg r -> row (l>>4)*4+r, col l&15.  [m89-verified, carried]

// ---- K0: split W (64x128) into 3 bf16 matrices in B-frag order (global) ----
__global__ __launch_bounds__(256) void k_wsplit(const float* __restrict__ W,
                                                unsigned short* __restrict__ ws) {
    for (int i = threadIdx.x; i < cD * cF; i += 256) {
        int d = i >> 7, f = i & 127;
        unsigned short s0, s1, s2;
        split3(W[i], s0, s1, s2);
        int n = f >> 4, k = d >> 5;
        int lane = (f & 15) | (((d >> 3) & 3) << 4);
        int j = d & 7;
        int base = ((n * 2 + k) * 3) * 512 + lane * 8 + j;
        ws[base]        = s0;
        ws[base + 512]  = s1;
        ws[base + 1024] = s2;
    }
}

// ---- staging transform: exp + cvt_pk split + swizzled frag-order store -----
// chunk = 32 rows x 64 cols = 512 float4; idx in [0,512). row = idx>>4 in [0,32).
// in-slot byte b0 = lane_frag*16 + jj*8 ; stored at b0 ^ (((b0>>8)&3)<<5).
__device__ __forceinline__ void transform_store(float4 a, int idx,
                                                unsigned short* __restrict__ af) {
    int row = idx >> 4, c4 = (idx & 15) * 4;
    float e0 = __expf(a.x), e1 = __expf(a.y), e2 = __expf(a.z), e3 = __expf(a.w);
    uint2 v0;
    v0.x = cvtpk(e0, e1);
    v0.y = cvtpk(e2, e3);
    float r0 = e0 - unpk_lo(v0.x), r1 = e1 - unpk_hi(v0.x);
    float r2 = e2 - unpk_lo(v0.y), r3 = e3 - unpk_hi(v0.y);
    uint2 v1;
    v1.x = cvtpk(r0, r1);
    v1.y = cvtpk(r2, r3);
    float t0 = r0 - unpk_lo(v1.x), t1 = r1 - unpk_hi(v1.x);
    float t2 = r2 - unpk_lo(v1.y), t3 = r3 - unpk_hi(v1.y);
    uint2 v2;
    v2.x = cvtpk(t0, t1);
    v2.y = cvtpk(t2, t3);

    int m = row >> 4, k = c4 >> 5;          // m in {0,1}
    int lane_frag = (row & 15) | (((c4 >> 3) & 3) << 4);
    int jj = (c4 & 7) >> 2;
    int b0 = lane_frag * 16 + jj * 8;
    int byte = b0 ^ (((b0 >> 8) & 3) << 5);
    char* dst = (char*)af + (m * 2 + k) * 3 * (SLOT * 2) + byte;
    *(uint2*)(dst)            = v0;
    *(uint2*)(dst + SLOT * 2) = v1;
    *(uint2*)(dst + SLOT * 4) = v2;
}

__device__ __forceinline__ void load_mat(const float4* __restrict__ src, int t,
                                         float4 ld[2]) {
#pragma unroll
    for (int i = 0; i < 2; ++i) ld[i] = src[t + i * THR];
}
__device__ __forceinline__ void write_mat(const float4 ld[2],
                                          unsigned short* __restrict__ af, int t) {
    transform_store(ld[0], t, af);
    transform_store(ld[1], t + THR, af);
}

__device__ __forceinline__ void read_frag(const unsigned short* __restrict__ af,
                                          int mk, int l, bf16x8* out3) {
    int b0 = l * 16;
    int byte = b0 ^ (((b0 >> 8) & 3) << 5);
    const char* p = (const char*)af + mk * 3 * (SLOT * 2) + byte;
    out3[0] = *(const bf16x8*)(p);
    out3[1] = *(const bf16x8*)(p + SLOT * 2);
    out3[2] = *(const bf16x8*)(p + SLOT * 4);
}

#define GEMM6(acc, A, Wf)            \
    acc = MFMA16(A[0], Wf[0], acc);  \
    acc = MFMA16(A[0], Wf[1], acc);  \
    acc = MFMA16(A[1], Wf[0], acc);  \
    acc = MFMA16(A[1], Wf[1], acc);  \
    acc = MFMA16(A[0], Wf[2], acc);  \
    acc = MFMA16(A[2], Wf[0], acc);

// merged K+V GEMM over 2 m-tiles x 2 n-tiles (wave w owns n-tiles 2w, 2w+1)
__device__ __forceinline__ void gemm_pass2(const unsigned short* __restrict__ afK,
                                           const unsigned short* __restrict__ afV,
                                           const unsigned short* __restrict__ wsplit,
                                           int w, int l,
                                           f32x4 accK[2][2], f32x4 accV[2][2]) {
#pragma unroll
    for (int k = 0; k < 2; ++k) {
        bf16x8 wf0[3], wf1[3];
#pragma unroll
        for (int p = 0; p < 3; ++p) {
            wf0[p] = *(const bf16x8*)(wsplit + (size_t)(((((2 * w + 0) * 2 + k) * 3 + p) * 512) + l * 8));
            wf1[p] = *(const bf16x8*)(wsplit + (size_t)(((((2 * w + 1) * 2 + k) * 3 + p) * 512) + l * 8));
        }
#pragma unroll
        for (int m = 0; m < 2; ++m) {
            bf16x8 aK[3], aV[3];
            read_frag(afK, m * 2 + k, l, aK);
            read_frag(afV, m * 2 + k, l, aV);
            GEMM6(accK[m][0], aK, wf0);
            GEMM6(accK[m][1], aK, wf1);
            GEMM6(accV[m][0], aV, wf0);
            GEMM6(accV[m][1], aV, wf1);
        }
    }
}

// Q GEMM (same geometry)
__device__ __forceinline__ void gemm_passQ(const unsigned short* __restrict__ af,
                                           const unsigned short* __restrict__ wsplit,
                                           int w, int l, f32x4 acc[2][2]) {
#pragma unroll
    for (int k = 0; k < 2; ++k) {
        bf16x8 wf0[3], wf1[3];
#pragma unroll
        for (int p = 0; p < 3; ++p) {
            wf0[p] = *(const bf16x8*)(wsplit + (size_t)(((((2 * w + 0) * 2 + k) * 3 + p) * 512) + l * 8));
            wf1[p] = *(const bf16x8*)(wsplit + (size_t)(((((2 * w + 1) * 2 + k) * 3 + p) * 512) + l * 8));
        }
#pragma unroll
        for (int m = 0; m < 2; ++m) {
            bf16x8 a[3];
            read_frag(af, m * 2 + k, l, a);
            GEMM6(acc[m][0], a, wf0);
            GEMM6(acc[m][1], a, wf1);
        }
    }
}

__device__ __forceinline__ unsigned long long agg_ld(const unsigned long long* p) {
    return __hip_atomic_load(p, __ATOMIC_RELAXED, __HIP_MEMORY_SCOPE_AGENT);
}

// ---- fused kernel ----------------------------------------------------------
__global__ __launch_bounds__(THR, 4) void k_main(const float* __restrict__ Q,
                                                 const float* __restrict__ K,
                                                 const float* __restrict__ V,
                                                 const unsigned short* __restrict__ wsplit,
                                                 float* __restrict__ out,
                                                 unsigned long long* __restrict__ agg)
{
    __shared__ unsigned short afK[12 * SLOT];   // 12480 B each; afK reused for Q
    __shared__ unsigned short afV[12 * SLOT];   // total 24960 B

    // XCD-grouped: all 32 blocks of batch b land on XCD b%8 (i = m*32 + b);
    // predecessors (smaller m) have smaller linear id.
    const int i0 = blockIdx.x;
    const int b = i0 & 31, m = i0 >> 5;          // 32 blocks per batch
    const int t = threadIdx.x, w = t >> 6, l = t & 63;
    const int col = l & 15, g = l >> 4;
    const int pid = w * 16 + col;                // feature-pair id in [0,64)

    // prologue: load chunk m
    float4 ldK[2], ldV[2];
    {
        const size_t rb = ((size_t)b * cS + (size_t)m * CHUNK) * cD;
        load_mat((const float4*)(K + rb), t, ldK);
        load_mat((const float4*)(V + rb), t, ldV);
    }
    float carK0 = 0.f, carV0 = 0.f, carK1 = 0.f, carV1 = 0.f;

    for (int j = 0; j < ITERS; ++j) {
        const int c = j * BPB + m;

        // ---- B0: prev iter's afK (Q-GEMM) reads done ----
        __syncthreads();
        write_mat(ldK, afK, t);
        write_mat(ldV, afV, t);
        if (j + 1 < ITERS) {
            const size_t rb = ((size_t)b * cS + (size_t)(c + BPB) * CHUNK) * cD;
            load_mat((const float4*)(K + rb), t, ldK);
            load_mat((const float4*)(V + rb), t, ldV);
        }
        __syncthreads();                       // B1: af ready

        // ---- issue Q loads (consumed after B2) ----
        float4 ldQ[2];
        {
            const size_t rb = ((size_t)b * cS + (size_t)c * CHUNK) * cD;
            load_mat((const float4*)(Q + rb), t, ldQ);
        }

        // ---- K and V feature GEMMs ----
        f32x4 accK[2][2] = {};
        f32x4 accV[2][2] = {};
        gemm_pass2(afK, afV, wsplit, w, l, accK, accV);

        // ---- gate: accK := k_s, accV := k_s * v_f ----
#pragma unroll
        for (int mm = 0; mm < 2; ++mm)
#pragma unroll
            for (int n = 0; n < 2; ++n)
#pragma unroll
                for (int r = 0; r < 4; ++r) {
                    float kf = accK[mm][n][r];
                    float ks = (kf > 0.5f) ? kf : 0.f;
                    accK[mm][n][r] = ks;
                    accV[mm][n][r] = ks * accV[mm][n][r];
                }

        // ---- fast chunk totals (fixed xor tree) + publish ASAP ----
        float kt[2], kvt[2];
#pragma unroll
        for (int n = 0; n < 2; ++n) {
            float a = 0.f, bb = 0.f;
#pragma unroll
            for (int mm = 0; mm < 2; ++mm)
#pragma unroll
                for (int r = 0; r < 4; ++r) {
                    a += accK[mm][n][r];
                    bb += accV[mm][n][r];
                }
            a += __shfl_xor(a, 16);
            a += __shfl_xor(a, 32);
            bb += __shfl_xor(bb, 16);
            bb += __shfl_xor(bb, 32);
            kt[n] = a;
            kvt[n] = bb;
        }
        if (g == 0) {
            unsigned long long u =
                  (unsigned long long)bf16rn(kt[0] + 1.0f)
                | ((unsigned long long)bf16rn(kvt[0]) << 16)
                | ((unsigned long long)bf16rn(kt[1] + 1.0f) << 32)
                | ((unsigned long long)bf16rn(kvt[1]) << 48);
            __hip_atomic_store(agg + (size_t)(b * NCH + c) * 64 + pid, u,
                               __ATOMIC_RELAXED, __HIP_MEMORY_SCOPE_AGENT);
        }

        // ---- issue walk loads (<=8/lane, independent) before cumsum ----
        const int lastc = (j == 0) ? -1 : (c - BPB);
        const int cc0 = c - 1 - g;
        const unsigned long long* base = agg + (size_t)b * NCH * 64 + pid;
        unsigned long long vv[8];
#pragma unroll
        for (int s2 = 0; s2 < 8; ++s2) {
            int cc = cc0 - 4 * s2;
            vv[s2] = (cc > lastc) ? agg_ld(base + (size_t)cc * 64) : 0ull;
        }

        // ---- in-chunk inclusive cumsum (serial VALU; hides walk latency) ----
#pragma unroll
        for (int n = 0; n < 2; ++n) {
            float cK = 0.f, cV = 0.f;
#pragma unroll
            for (int mm = 0; mm < 2; ++mm) {
                f32x4 aK = accK[mm][n], aV = accV[mm][n];
                aK[1] += aK[0]; aK[2] += aK[1]; aK[3] += aK[2];
                aV[1] += aV[0]; aV[2] += aV[1]; aV[3] += aV[2];
                float tK = aK[3], tV = aV[3];
                float uK = __shfl_up(tK, 16), uV = __shfl_up(tV, 16);
                if (g >= 1) { tK += uK; tV += uV; }
                float xK = __shfl_up(tK, 32), xV = __shfl_up(tV, 32);
                if (g >= 2) { tK += xK; tV += xV; }
                float eK = tK - aK[3] + cK;
                float eV = tV - aV[3] + cV;
                aK[0] += eK; aK[1] += eK; aK[2] += eK; aK[3] += eK;
                aV[0] += eV; aV[1] += eV; aV[2] += eV; aV[3] += eV;
                accK[mm][n] = aK; accV[mm][n] = aV;
                cK += __shfl(tK, 48 + col);
                cV += __shfl(tV, 48 + col);
            }
        }

        // ---- finish walk: check/retry (rare), fixed xor-tree combine ----
        {
            float dk0 = 0.f, dv0 = 0.f, dk1 = 0.f, dv1 = 0.f;
#pragma unroll
            for (int s2 = 0; s2 < 8; ++s2) {
                int cc = cc0 - 4 * s2;
                if (cc > lastc) {
                    unsigned long long v0 = vv[s2];
                    while ((v0 & 0xFFFFull) == 0ull) v0 = agg_ld(base + (size_t)cc * 64);
                    dk0 += bf16tof((unsigned short)(v0 & 0xFFFF)) - 1.0f;
                    dv0 += bf16tof((unsigned short)((v0 >> 16) & 0xFFFF));
                    dk1 += bf16tof((unsigned short)((v0 >> 32) & 0xFFFF)) - 1.0f;
                    dv1 += bf16tof((unsigned short)((v0 >> 48) & 0xFFFF));
                }
            }
            dk0 += __shfl_xor(dk0, 16); dk0 += __shfl_xor(dk0, 32);
            dv0 += __shfl_xor(dv0, 16); dv0 += __shfl_xor(dv0, 32);
            dk1 += __shfl_xor(dk1, 16); dk1 += __shfl_xor(dk1, 32);
            dv1 += __shfl_xor(dv1, 16); dv1 += __shfl_xor(dv1, 32);
            carK0 += dk0; carV0 += dv0;        // prefix through c-1
            carK1 += dk1; carV1 += dv1;
        }

        // ---- attn in place: accV := attn (accK dead after) ----
#pragma unroll
        for (int mm = 0; mm < 2; ++mm)
#pragma unroll
            for (int n = 0; n < 2; ++n)
#pragma unroll
                for (int r = 0; r < 4; ++r) {
                    float pK = n ? carK1 : carK0;
                    float pV = n ? carV1 : carV0;
                    float kc = accK[mm][n][r] + pK;
                    float vc = accV[mm][n][r] + pV;
                    accV[mm][n][r] = __fdividef(vc + EPS_, kc + EPS_);
                }
        carK0 += kt[0]; carV0 += kvt[0];       // prefix through c (incl own)
        carK1 += kt[1]; carV1 += kvt[1];

        // ---- B2: all waves' K/V GEMM reads done -> restage Q into afK ----
        __syncthreads();
        write_mat(ldQ, afK, t);
        __syncthreads();                       // B3: Q staged

        // ---- Q feature GEMM + output ----
        f32x4 accQ[2][2] = {};
        gemm_passQ(afK, wsplit, w, l, accQ);

        const size_t obase = ((size_t)b * cS + (size_t)c * CHUNK) * cF;
#pragma unroll
        for (int mm = 0; mm < 2; ++mm)
#pragma unroll
            for (int n = 0; n < 2; ++n)
#pragma unroll
                for (int r = 0; r < 4; ++r) {
                    int s = mm * 16 + g * 4 + r;
                    int f = w * 32 + n * 16 + col;
                    float qf = accQ[mm][n][r];
                    float qs = (qf > 0.5f) ? qf : 0.f;
                    out[obase + (size_t)s * cF + f] = qs * accV[mm][n][r];
                }
    }
}

// ---------------------------------------------------------------------------
extern "C" void kernel_launch(void* const* d_in, const int* in_sizes, int n_in,
                              void* d_out, int out_size, void* d_ws, size_t ws_size,
                              hipStream_t stream) {
    const float* q = (const float*)d_in[0];
    const float* k = (const float*)d_in[1];
    const float* v = (const float*)d_in[2];
    const float* w = (const float*)d_in[3];
    float* out = (float*)d_out;

    unsigned short* wsplit = (unsigned short*)d_ws;                       // 48 KiB
    unsigned long long* agg = (unsigned long long*)((char*)d_ws + 65536); // 4 MiB

    hipMemsetAsync(agg, 0, (size_t)cB * NCH * 64 * sizeof(unsigned long long), stream);
    k_wsplit<<<1, 256, 0, stream>>>(w, wsplit);
    k_main<<<cB * BPB, THR, 0, stream>>>(q, k, v, wsplit, out, agg);
}

// Round 18
// 152.511 us; speedup vs baseline: 1.4570x; 1.4570x over previous
//
#include <hip/hip_runtime.h>

// SpikingLinearAttention forward — fused chunk-scan kernel, v16.
//  = v13 (R15, 137.7us best) with ONE scheduling fix, zero math change:
//  v13 issued next-iter K/V/Q prefetch loads BETWEEN write_mat and B2; since
//  __syncthreads() drains vmcnt(0), every iteration stalled ~900cyc at B2 on
//  loads issued moments earlier — the cross-iteration prefetch never happened.
//  v16 issues them AFTER the walk-poll loads (polls older in vmcnt FIFO order,
//  so walk-finish waits only on polls): prefetch then flies under
//  cumsum+walk+attn (~950cyc) and is drained for free at the Q-GEMM wf loads /
//  next B1.
//  Carried from v13: merged K/V GEMM (8 chains), XCD-grouped mapping,
//  6-term bf16-split MFMA (f32-dot precision), f32 gate, in-register in-chunk
//  cumsum (MFMA C/D layout), deterministic decoupled lookback (8B atomics).

constexpr int cB = 32;
constexpr int cS = 8192;
constexpr int cD = 64;
constexpr int cF = 128;
constexpr int CHUNK = 64;
constexpr int NCH = cS / CHUNK;   // 128 chunks per batch
constexpr int SLOT = 520;         // ushorts per p-plane slot (1040 B)
constexpr int THR = 512;          // 8 waves
constexpr int BPB = 16;           // blocks per batch
constexpr int ITERS = NCH / BPB;  // 8 chunks per block, stride BPB
constexpr float EPS_ = 1e-8f;

typedef __attribute__((ext_vector_type(8))) short bf16x8;  // 8 bf16 (4 VGPRs)
typedef __attribute__((ext_vector_type(4))) float f32x4;   // 4 f32 acc

#define MFMA16(a, b, c) __builtin_amdgcn_mfma_f32_16x16x32_bf16((a), (b), (c), 0, 0, 0)

// ---- bf16 helpers ----------------------------------------------------------
__device__ __forceinline__ unsigned short bf16rn(float x) {
    unsigned u = __float_as_uint(x);
    unsigned r = u + 0x7FFFu + ((u >> 16) & 1u);
    return (unsigned short)(r >> 16);
}
__device__ __forceinline__ float bf16tof(unsigned short h) {
    return __uint_as_float((unsigned)h << 16);
}
__device__ __forceinline__ void split3(float x, unsigned short& a0,
                                       unsigned short& a1, unsigned short& a2) {
    a0 = bf16rn(x);
    float r1 = x - bf16tof(a0);
    a1 = bf16rn(r1);
    float r2 = r1 - bf16tof(a1);
    a2 = bf16rn(r2);
}
// packed RNE bf16 pair (same rounding as bf16rn -> numerically identical)
__device__ __forceinline__ unsigned cvtpk(float lo, float hi) {
    unsigned r;
    asm("v_cvt_pk_bf16_f32 %0, %1, %2" : "=v"(r) : "v"(lo), "v"(hi));
    return r;
}
__device__ __forceinline__ float unpk_lo(unsigned u) {
    return __uint_as_float(u << 16);
}
__device__ __forceinline__ float unpk_hi(unsigned u) {
    return __uint_as_float(u & 0xFFFF0000u);
}

// A-frag: lane l holds A[l&15][(l>>4)*8+j].  B-frag: lane l holds B[(l>>4)*8+j][l&15].
// C/D: lane l, reg r -> row (l>>4)*4+r, col l&15.  [m89-verified, carried]

// ---- K0: split W (64x128) into 3 bf16 matrices in B-frag order (global) ----
__global__ __launch_bounds__(256) void k_wsplit(const float* __restrict__ W,
                                                unsigned short* __restrict__ ws) {
    for (int i = threadIdx.x; i < cD * cF; i += 256) {
        int d = i >> 7, f = i & 127;
        unsigned short s0, s1, s2;
        split3(W[i], s0, s1, s2);
        int n = f >> 4, k = d >> 5;
        int lane = (f & 15) | (((d >> 3) & 3) << 4);
        int j = d & 7;
        int base = ((n * 2 + k) * 3) * 512 + lane * 8 + j;
        ws[base]        = s0;
        ws[base + 512]  = s1;
        ws[base + 1024] = s2;
    }
}

// ---- staging transform: exp + cvt_pk split + swizzled frag-order store -----
// in-slot byte b0 = lane_frag*16 + jj*8 ; stored at b0 ^ (((b0>>8)&3)<<5).
__device__ __forceinline__ void transform_store(float4 a, int idx,
                                                unsigned short* __restrict__ af) {
    int row = idx >> 4, c4 = (idx & 15) * 4;
    float e0 = __expf(a.x), e1 = __expf(a.y), e2 = __expf(a.z), e3 = __expf(a.w);
    uint2 v0;
    v0.x = cvtpk(e0, e1);
    v0.y = cvtpk(e2, e3);
    float r0 = e0 - unpk_lo(v0.x), r1 = e1 - unpk_hi(v0.x);
    float r2 = e2 - unpk_lo(v0.y), r3 = e3 - unpk_hi(v0.y);
    uint2 v1;
    v1.x = cvtpk(r0, r1);
    v1.y = cvtpk(r2, r3);
    float t0 = r0 - unpk_lo(v1.x), t1 = r1 - unpk_hi(v1.x);
    float t2 = r2 - unpk_lo(v1.y), t3 = r3 - unpk_hi(v1.y);
    uint2 v2;
    v2.x = cvtpk(t0, t1);
    v2.y = cvtpk(t2, t3);

    int m = row >> 4, k = c4 >> 5;
    int lane_frag = (row & 15) | (((c4 >> 3) & 3) << 4);
    int jj = (c4 & 7) >> 2;
    int b0 = lane_frag * 16 + jj * 8;
    int byte = b0 ^ (((b0 >> 8) & 3) << 5);
    char* dst = (char*)af + (m * 2 + k) * 3 * (SLOT * 2) + byte;
    *(uint2*)(dst)            = v0;
    *(uint2*)(dst + SLOT * 2) = v1;
    *(uint2*)(dst + SLOT * 4) = v2;
}

__device__ __forceinline__ void load_mat(const float4* __restrict__ src, int t,
                                         float4 ld[2]) {
#pragma unroll
    for (int i = 0; i < 2; ++i) ld[i] = src[t + i * THR];
}
__device__ __forceinline__ void write_mat(const float4 ld[2],
                                          unsigned short* __restrict__ af, int t) {
    transform_store(ld[0], t, af);
    transform_store(ld[1], t + THR, af);
}

__device__ __forceinline__ void read_frag(const unsigned short* __restrict__ af,
                                          int mk, int l, bf16x8* out3) {
    int b0 = l * 16;
    int byte = b0 ^ (((b0 >> 8) & 3) << 5);
    const char* p = (const char*)af + mk * 3 * (SLOT * 2) + byte;
    out3[0] = *(const bf16x8*)(p);
    out3[1] = *(const bf16x8*)(p + SLOT * 2);
    out3[2] = *(const bf16x8*)(p + SLOT * 4);
}

#define GEMM6(acc, A, Wf)            \
    acc = MFMA16(A[0], Wf[0], acc);  \
    acc = MFMA16(A[0], Wf[1], acc);  \
    acc = MFMA16(A[1], Wf[0], acc);  \
    acc = MFMA16(A[1], Wf[1], acc);  \
    acc = MFMA16(A[0], Wf[2], acc);  \
    acc = MFMA16(A[2], Wf[0], acc);

// single-matrix GEMM (used for Q): wave w owns n-tile n=w
__device__ __forceinline__ void gemm_pass(const unsigned short* __restrict__ af,
                                          const unsigned short* __restrict__ wsplit,
                                          int w, int l, f32x4 acc[4]) {
#pragma unroll
    for (int k = 0; k < 2; ++k) {
        bf16x8 wf[3];
#pragma unroll
        for (int p = 0; p < 3; ++p)
            wf[p] = *(const bf16x8*)(wsplit + (size_t)((((w * 2 + k) * 3 + p) * 512) + l * 8));
#pragma unroll
        for (int m = 0; m < 4; ++m) {
            bf16x8 a[3];
            read_frag(af, m * 2 + k, l, a);
            GEMM6(acc[m], a, wf);
        }
    }
}

// merged K+V GEMM: 8 independent accumulator chains, shared W-frags
__device__ __forceinline__ void gemm_pass2(const unsigned short* __restrict__ afK,
                                           const unsigned short* __restrict__ afV,
                                           const unsigned short* __restrict__ wsplit,
                                           int w, int l,
                                           f32x4 accK[4], f32x4 accV[4]) {
#pragma unroll
    for (int k = 0; k < 2; ++k) {
        bf16x8 wf[3];
#pragma unroll
        for (int p = 0; p < 3; ++p)
            wf[p] = *(const bf16x8*)(wsplit + (size_t)((((w * 2 + k) * 3 + p) * 512) + l * 8));
#pragma unroll
        for (int m = 0; m < 4; ++m) {
            bf16x8 aK[3], aV[3];
            read_frag(afK, m * 2 + k, l, aK);
            read_frag(afV, m * 2 + k, l, aV);
            GEMM6(accK[m], aK, wf);
            GEMM6(accV[m], aV, wf);
        }
    }
}

__device__ __forceinline__ unsigned long long agg_ld(const unsigned long long* p) {
    return __hip_atomic_load(p, __ATOMIC_RELAXED, __HIP_MEMORY_SCOPE_AGENT);
}

// ---- fused kernel ----------------------------------------------------------
__global__ __launch_bounds__(THR, 4) void k_main(const float* __restrict__ Q,
                                                 const float* __restrict__ K,
                                                 const float* __restrict__ V,
                                                 const unsigned short* __restrict__ wsplit,
                                                 float* __restrict__ out,
                                                 unsigned long long* __restrict__ agg)
{
    __shared__ unsigned short afK[24 * SLOT];   // 24960 B each, 74880 total
    __shared__ unsigned short afV[24 * SLOT];
    __shared__ unsigned short afQ[24 * SLOT];

    // XCD-grouped: all 16 blocks of batch b land on XCD b%8 (i = m*32 + b);
    // predecessors (smaller m) have smaller linear id.
    const int i0 = blockIdx.x;
    const int b = i0 & 31, m = i0 >> 5;          // 16 blocks per batch
    const int t = threadIdx.x, w = t >> 6, l = t & 63;
    const int col = l & 15, g = l >> 4;
    const int fidx = w * 16 + col;

    // prologue: load chunk m
    float4 ldK[2], ldV[2], ldQ[2];
    {
        const size_t rb = ((size_t)b * cS + (size_t)m * CHUNK) * cD;
        load_mat((const float4*)(K + rb), t, ldK);
        load_mat((const float4*)(V + rb), t, ldV);
        load_mat((const float4*)(Q + rb), t, ldQ);
    }
    float carK = 0.f, carV = 0.f;   // prefix through previous own chunk (incl)

    for (int j = 0; j < ITERS; ++j) {
        const int c = j * BPB + m;

        // ---- stage current chunk (no loads outstanding at B2 -> cheap drain) ----
        __syncthreads();                       // B1: af free (prev iter reads done)
        write_mat(ldK, afK, t);
        write_mat(ldV, afV, t);
        write_mat(ldQ, afQ, t);
        __syncthreads();                       // B2: af ready

        // ---- K and V feature GEMMs (merged, 8 independent chains) ----
        f32x4 accK[4] = {};
        f32x4 accV[4] = {};
        gemm_pass2(afK, afV, wsplit, w, l, accK, accV);

        // ---- gate: accK := k_s, accV := k_s * v_f ----
#pragma unroll
        for (int mm = 0; mm < 4; ++mm)
#pragma unroll
            for (int r = 0; r < 4; ++r) {
                float kf = accK[mm][r];
                float ks = (kf > 0.5f) ? kf : 0.f;
                accK[mm][r] = ks;
                accV[mm][r] = ks * accV[mm][r];
            }

        // ---- fast chunk totals (fixed xor tree) + publish ASAP ----
        float ktot = 0.f, kvtot = 0.f;
#pragma unroll
        for (int mm = 0; mm < 4; ++mm)
#pragma unroll
            for (int r = 0; r < 4; ++r) {
                ktot += accK[mm][r];
                kvtot += accV[mm][r];
            }
        ktot += __shfl_xor(ktot, 16);
        ktot += __shfl_xor(ktot, 32);
        kvtot += __shfl_xor(kvtot, 16);
        kvtot += __shfl_xor(kvtot, 32);
        if (g == 0) {
            unsigned long long u = ((unsigned long long)__float_as_uint(kvtot) << 32)
                                 | (unsigned long long)__float_as_uint(ktot + 1.0f);
            __hip_atomic_store(agg + (size_t)(b * NCH + c) * cF + fidx, u,
                               __ATOMIC_RELAXED, __HIP_MEMORY_SCOPE_AGENT);
        }

        // ---- issue walk polls FIRST (older in vmcnt FIFO than prefetch) ----
        const int lastc = (j == 0) ? -1 : (c - BPB);
        const int cc0 = c - 1 - g;
        const unsigned long long* base = agg + (size_t)b * NCH * cF + fidx;
        unsigned long long vv[4];
#pragma unroll
        for (int s2 = 0; s2 < 4; ++s2) {
            int cc = cc0 - 4 * s2;
            vv[s2] = (cc > lastc) ? agg_ld(base + (size_t)cc * cF) : 0ull;
        }

        // ---- prefetch next chunk NOW: flies under cumsum+walk+attn, drains
        //      for free at Q-GEMM wf loads / next B1 (v13 drained it at B2) ----
        if (j + 1 < ITERS) {
            const size_t rb = ((size_t)b * cS + (size_t)(c + BPB) * CHUNK) * cD;
            load_mat((const float4*)(K + rb), t, ldK);
            load_mat((const float4*)(V + rb), t, ldV);
            load_mat((const float4*)(Q + rb), t, ldQ);
        }

        // ---- in-chunk inclusive cumsum (serial VALU; hides poll latency) ----
        {
            float cK = 0.f, cV = 0.f;
#pragma unroll
            for (int mm = 0; mm < 4; ++mm) {
                f32x4 aK = accK[mm], aV = accV[mm];
                aK[1] += aK[0]; aK[2] += aK[1]; aK[3] += aK[2];
                aV[1] += aV[0]; aV[2] += aV[1]; aV[3] += aV[2];
                float tK = aK[3], tV = aV[3];
                float uK = __shfl_up(tK, 16), uV = __shfl_up(tV, 16);
                if (g >= 1) { tK += uK; tV += uV; }
                float xK = __shfl_up(tK, 32), xV = __shfl_up(tV, 32);
                if (g >= 2) { tK += xK; tV += xV; }
                float eK = tK - aK[3] + cK;
                float eV = tV - aV[3] + cV;
                aK[0] += eK; aK[1] += eK; aK[2] += eK; aK[3] += eK;
                aV[0] += eV; aV[1] += eV; aV[2] += eV; aV[3] += eV;
                accK[mm] = aK; accV[mm] = aV;
                cK += __shfl(tK, 48 + col);
                cV += __shfl(tV, 48 + col);
            }
        }

        // ---- finish walk: check/retry (rare), fixed xor-tree combine ----
        {
            float dk = 0.f, dv = 0.f;
#pragma unroll
            for (int s2 = 0; s2 < 4; ++s2) {
                int cc = cc0 - 4 * s2;
                if (cc > lastc) {
                    unsigned long long v0 = vv[s2];
                    while ((unsigned)v0 == 0u) v0 = agg_ld(base + (size_t)cc * cF);
                    dk += __uint_as_float((unsigned)v0) - 1.0f;
                    dv += __uint_as_float((unsigned)(v0 >> 32));
                }
            }
            dk += __shfl_xor(dk, 16);
            dk += __shfl_xor(dk, 32);
            dv += __shfl_xor(dv, 16);
            dv += __shfl_xor(dv, 32);
            carK += dk;            // now = prefix through c-1
            carV += dv;
        }

        // ---- attn in place: accV := attn (accK dead after) ----
#pragma unroll
        for (int mm = 0; mm < 4; ++mm)
#pragma unroll
            for (int r = 0; r < 4; ++r) {
                float kc = accK[mm][r] + carK;
                float vc = accV[mm][r] + carV;
                accV[mm][r] = __fdividef(vc + EPS_, kc + EPS_);
            }
        carK += ktot;              // prefix through c (incl own chunk)
        carV += kvtot;

        // ---- Q feature GEMM + output ----
        f32x4 accQ[4] = {};
        gemm_pass(afQ, wsplit, w, l, accQ);

        const size_t obase = ((size_t)b * cS + (size_t)c * CHUNK) * cF;
#pragma unroll
        for (int mm = 0; mm < 4; ++mm)
#pragma unroll
            for (int r = 0; r < 4; ++r) {
                int s = mm * 16 + g * 4 + r;
                float qf = accQ[mm][r];
                float qs = (qf > 0.5f) ? qf : 0.f;
                out[obase + (size_t)s * cF + fidx] = qs * accV[mm][r];
            }
    }
}

// ---------------------------------------------------------------------------
extern "C" void kernel_launch(void* const* d_in, const int* in_sizes, int n_in,
                              void* d_out, int out_size, void* d_ws, size_t ws_size,
                              hipStream_t stream) {
    const float* q = (const float*)d_in[0];
    const float* k = (const float*)d_in[1];
    const float* v = (const float*)d_in[2];
    const float* w = (const float*)d_in[3];
    float* out = (float*)d_out;

    unsigned short* wsplit = (unsigned short*)d_ws;                       // 48 KiB
    unsigned long long* agg = (unsigned long long*)((char*)d_ws + 65536); // 4 MiB

    hipMemsetAsync(agg, 0, (size_t)cB * NCH * cF * sizeof(unsigned long long), stream);
    k_wsplit<<<1, 256, 0, stream>>>(w, wsplit);
    k_main<<<cB * BPB, THR, 0, stream>>>(q, k, v, wsplit, out, agg);
}

// Round 19
// 139.347 us; speedup vs baseline: 1.5946x; 1.0945x over previous
//
#include <hip/hip_runtime.h>

// SpikingLinearAttention forward — fused chunk-scan kernel, v13 (FINAL; best measured).
//  R15: 137.7us. Reverted to after v14/v15/v16 perturbations all regressed.
//  Structure: 512 blocks (16/batch, 8 chunks each, stride 16, in-register
//  carry), 8 waves, 3 af LDS buffers (75KB), 2 barriers/iter, launch_bounds(512,4).
//  (a) MERGED K/V GEMM loop: 8 independent MFMA accumulator chains, one
//      ds_read pair feeds two GEMM6 clusters.
//  (b) XCD-grouped mapping b=i&31, m=i>>5: a batch's 16 lookback peers share
//      one XCD -> publish/poll at local-L2 latency; predecessors keep smaller
//      linear ids (in-order dispatch argument).
//  features = exp(X) @ W via 6-term bf16-split MFMA (f32-dot precision)
//  gate in f32, in-chunk cumsum IN REGISTERS (MFMA C/D layout), cross-chunk
//  prefix via deterministic decoupled lookback (8B agent atomics).
//  Empirical constraints mapped over R7-R18: 16 waves/CU hard floor (reg
//  budget steps 64/128/256; ~96 live regs irreducible); any 3-acc overlap
//  spills; per-iter lookback rendezvous ~free; prefetch-at-staging beats
//  prefetch-post-poll (retry loop forces vmcnt(0) drain of younger loads).

constexpr int cB = 32;
constexpr int cS = 8192;
constexpr int cD = 64;
constexpr int cF = 128;
constexpr int CHUNK = 64;
constexpr int NCH = cS / CHUNK;   // 128 chunks per batch
constexpr int SLOT = 520;         // ushorts per p-plane slot (1040 B)
constexpr int THR = 512;          // 8 waves
constexpr int BPB = 16;           // blocks per batch
constexpr int ITERS = NCH / BPB;  // 8 chunks per block, stride BPB
constexpr float EPS_ = 1e-8f;

typedef __attribute__((ext_vector_type(8))) short bf16x8;  // 8 bf16 (4 VGPRs)
typedef __attribute__((ext_vector_type(4))) float f32x4;   // 4 f32 acc

#define MFMA16(a, b, c) __builtin_amdgcn_mfma_f32_16x16x32_bf16((a), (b), (c), 0, 0, 0)

// ---- bf16 helpers ----------------------------------------------------------
__device__ __forceinline__ unsigned short bf16rn(float x) {
    unsigned u = __float_as_uint(x);
    unsigned r = u + 0x7FFFu + ((u >> 16) & 1u);
    return (unsigned short)(r >> 16);
}
__device__ __forceinline__ float bf16tof(unsigned short h) {
    return __uint_as_float((unsigned)h << 16);
}
__device__ __forceinline__ void split3(float x, unsigned short& a0,
                                       unsigned short& a1, unsigned short& a2) {
    a0 = bf16rn(x);
    float r1 = x - bf16tof(a0);
    a1 = bf16rn(r1);
    float r2 = r1 - bf16tof(a1);
    a2 = bf16rn(r2);
}
// packed RNE bf16 pair (same rounding as bf16rn -> numerically identical)
__device__ __forceinline__ unsigned cvtpk(float lo, float hi) {
    unsigned r;
    asm("v_cvt_pk_bf16_f32 %0, %1, %2" : "=v"(r) : "v"(lo), "v"(hi));
    return r;
}
__device__ __forceinline__ float unpk_lo(unsigned u) {
    return __uint_as_float(u << 16);
}
__device__ __forceinline__ float unpk_hi(unsigned u) {
    return __uint_as_float(u & 0xFFFF0000u);
}

// A-frag: lane l holds A[l&15][(l>>4)*8+j].  B-frag: lane l holds B[(l>>4)*8+j][l&15].
// C/D: lane l, reg r -> row (l>>4)*4+r, col l&15.  [m89-verified, carried]

// ---- K0: split W (64x128) into 3 bf16 matrices in B-frag order (global) ----
__global__ __launch_bounds__(256) void k_wsplit(const float* __restrict__ W,
                                                unsigned short* __restrict__ ws) {
    for (int i = threadIdx.x; i < cD * cF; i += 256) {
        int d = i >> 7, f = i & 127;
        unsigned short s0, s1, s2;
        split3(W[i], s0, s1, s2);
        int n = f >> 4, k = d >> 5;
        int lane = (f & 15) | (((d >> 3) & 3) << 4);
        int j = d & 7;
        int base = ((n * 2 + k) * 3) * 512 + lane * 8 + j;
        ws[base]        = s0;
        ws[base + 512]  = s1;
        ws[base + 1024] = s2;
    }
}

// ---- staging transform: exp + cvt_pk split + swizzled frag-order store -----
// in-slot byte b0 = lane_frag*16 + jj*8 ; stored at b0 ^ (((b0>>8)&3)<<5).
__device__ __forceinline__ void transform_store(float4 a, int idx,
                                                unsigned short* __restrict__ af) {
    int row = idx >> 4, c4 = (idx & 15) * 4;
    float e0 = __expf(a.x), e1 = __expf(a.y), e2 = __expf(a.z), e3 = __expf(a.w);
    uint2 v0;
    v0.x = cvtpk(e0, e1);
    v0.y = cvtpk(e2, e3);
    float r0 = e0 - unpk_lo(v0.x), r1 = e1 - unpk_hi(v0.x);
    float r2 = e2 - unpk_lo(v0.y), r3 = e3 - unpk_hi(v0.y);
    uint2 v1;
    v1.x = cvtpk(r0, r1);
    v1.y = cvtpk(r2, r3);
    float t0 = r0 - unpk_lo(v1.x), t1 = r1 - unpk_hi(v1.x);
    float t2 = r2 - unpk_lo(v1.y), t3 = r3 - unpk_hi(v1.y);
    uint2 v2;
    v2.x = cvtpk(t0, t1);
    v2.y = cvtpk(t2, t3);

    int m = row >> 4, k = c4 >> 5;
    int lane_frag = (row & 15) | (((c4 >> 3) & 3) << 4);
    int jj = (c4 & 7) >> 2;
    int b0 = lane_frag * 16 + jj * 8;
    int byte = b0 ^ (((b0 >> 8) & 3) << 5);
    char* dst = (char*)af + (m * 2 + k) * 3 * (SLOT * 2) + byte;
    *(uint2*)(dst)            = v0;
    *(uint2*)(dst + SLOT * 2) = v1;
    *(uint2*)(dst + SLOT * 4) = v2;
}

__device__ __forceinline__ void load_mat(const float4* __restrict__ src, int t,
                                         float4 ld[2]) {
#pragma unroll
    for (int i = 0; i < 2; ++i) ld[i] = src[t + i * THR];
}
__device__ __forceinline__ void write_mat(const float4 ld[2],
                                          unsigned short* __restrict__ af, int t) {
    transform_store(ld[0], t, af);
    transform_store(ld[1], t + THR, af);
}

__device__ __forceinline__ void read_frag(const unsigned short* __restrict__ af,
                                          int mk, int l, bf16x8* out3) {
    int b0 = l * 16;
    int byte = b0 ^ (((b0 >> 8) & 3) << 5);
    const char* p = (const char*)af + mk * 3 * (SLOT * 2) + byte;
    out3[0] = *(const bf16x8*)(p);
    out3[1] = *(const bf16x8*)(p + SLOT * 2);
    out3[2] = *(const bf16x8*)(p + SLOT * 4);
}

#define GEMM6(acc, A, Wf)            \
    acc = MFMA16(A[0], Wf[0], acc);  \
    acc = MFMA16(A[0], Wf[1], acc);  \
    acc = MFMA16(A[1], Wf[0], acc);  \
    acc = MFMA16(A[1], Wf[1], acc);  \
    acc = MFMA16(A[0], Wf[2], acc);  \
    acc = MFMA16(A[2], Wf[0], acc);

// single-matrix GEMM (used for Q): wave w owns n-tile n=w
__device__ __forceinline__ void gemm_pass(const unsigned short* __restrict__ af,
                                          const unsigned short* __restrict__ wsplit,
                                          int w, int l, f32x4 acc[4]) {
#pragma unroll
    for (int k = 0; k < 2; ++k) {
        bf16x8 wf[3];
#pragma unroll
        for (int p = 0; p < 3; ++p)
            wf[p] = *(const bf16x8*)(wsplit + (size_t)((((w * 2 + k) * 3 + p) * 512) + l * 8));
#pragma unroll
        for (int m = 0; m < 4; ++m) {
            bf16x8 a[3];
            read_frag(af, m * 2 + k, l, a);
            GEMM6(acc[m], a, wf);
        }
    }
}

// merged K+V GEMM: 8 independent accumulator chains, shared W-frags,
// one ds_read pair per sub-tile feeds two GEMM6 clusters.
__device__ __forceinline__ void gemm_pass2(const unsigned short* __restrict__ afK,
                                           const unsigned short* __restrict__ afV,
                                           const unsigned short* __restrict__ wsplit,
                                           int w, int l,
                                           f32x4 accK[4], f32x4 accV[4]) {
#pragma unroll
    for (int k = 0; k < 2; ++k) {
        bf16x8 wf[3];
#pragma unroll
        for (int p = 0; p < 3; ++p)
            wf[p] = *(const bf16x8*)(wsplit + (size_t)((((w * 2 + k) * 3 + p) * 512) + l * 8));
#pragma unroll
        for (int m = 0; m < 4; ++m) {
            bf16x8 aK[3], aV[3];
            read_frag(afK, m * 2 + k, l, aK);
            read_frag(afV, m * 2 + k, l, aV);
            GEMM6(accK[m], aK, wf);
            GEMM6(accV[m], aV, wf);
        }
    }
}

__device__ __forceinline__ unsigned long long agg_ld(const unsigned long long* p) {
    return __hip_atomic_load(p, __ATOMIC_RELAXED, __HIP_MEMORY_SCOPE_AGENT);
}

// ---- fused kernel ----------------------------------------------------------
__global__ __launch_bounds__(THR, 4) void k_main(const float* __restrict__ Q,
                                                 const float* __restrict__ K,
                                                 const float* __restrict__ V,
                                                 const unsigned short* __restrict__ wsplit,
                                                 float* __restrict__ out,
                                                 unsigned long long* __restrict__ agg)
{
    __shared__ unsigned short afK[24 * SLOT];   // 24960 B each, 74880 total
    __shared__ unsigned short afV[24 * SLOT];
    __shared__ unsigned short afQ[24 * SLOT];

    // XCD-grouped: all 16 blocks of batch b land on XCD b%8 (i = m*32 + b,
    // 32 == 0 mod 8); predecessors (smaller m) have smaller linear id.
    const int i0 = blockIdx.x;
    const int b = i0 & 31, m = i0 >> 5;          // 16 blocks per batch
    const int t = threadIdx.x, w = t >> 6, l = t & 63;
    const int col = l & 15, g = l >> 4;
    const int fidx = w * 16 + col;

    // prologue: load chunk m
    float4 ldK[2], ldV[2], ldQ[2];
    {
        const size_t rb = ((size_t)b * cS + (size_t)m * CHUNK) * cD;
        load_mat((const float4*)(K + rb), t, ldK);
        load_mat((const float4*)(V + rb), t, ldV);
        load_mat((const float4*)(Q + rb), t, ldQ);
    }
    float carK = 0.f, carV = 0.f;   // prefix through previous own chunk (incl)

    for (int j = 0; j < ITERS; ++j) {
        const int c = j * BPB + m;

        // ---- stage current chunk; issue next chunk's loads ----
        __syncthreads();                       // af free (prev iter reads done)
        write_mat(ldK, afK, t);
        write_mat(ldV, afV, t);
        write_mat(ldQ, afQ, t);
        if (j + 1 < ITERS) {
            const size_t rb = ((size_t)b * cS + (size_t)(c + BPB) * CHUNK) * cD;
            load_mat((const float4*)(K + rb), t, ldK);
            load_mat((const float4*)(V + rb), t, ldV);
            load_mat((const float4*)(Q + rb), t, ldQ);
        }
        __syncthreads();                       // af ready

        // ---- K and V feature GEMMs (merged, 8 independent chains) ----
        f32x4 accK[4] = {};
        f32x4 accV[4] = {};
        gemm_pass2(afK, afV, wsplit, w, l, accK, accV);

        // ---- gate: accK := k_s, accV := k_s * v_f ----
#pragma unroll
        for (int mm = 0; mm < 4; ++mm)
#pragma unroll
            for (int r = 0; r < 4; ++r) {
                float kf = accK[mm][r];
                float ks = (kf > 0.5f) ? kf : 0.f;
                accK[mm][r] = ks;
                accV[mm][r] = ks * accV[mm][r];
            }

        // ---- fast chunk totals (fixed xor tree) + publish ASAP ----
        float ktot = 0.f, kvtot = 0.f;
#pragma unroll
        for (int mm = 0; mm < 4; ++mm)
#pragma unroll
            for (int r = 0; r < 4; ++r) {
                ktot += accK[mm][r];
                kvtot += accV[mm][r];
            }
        ktot += __shfl_xor(ktot, 16);
        ktot += __shfl_xor(ktot, 32);
        kvtot += __shfl_xor(kvtot, 16);
        kvtot += __shfl_xor(kvtot, 32);
        if (g == 0) {
            unsigned long long u = ((unsigned long long)__float_as_uint(kvtot) << 32)
                                 | (unsigned long long)__float_as_uint(ktot + 1.0f);
            __hip_atomic_store(agg + (size_t)(b * NCH + c) * cF + fidx, u,
                               __ATOMIC_RELAXED, __HIP_MEMORY_SCOPE_AGENT);
        }

        // ---- issue walk loads (<=4/lane, independent) before cumsum ----
        const int lastc = (j == 0) ? -1 : (c - BPB);
        const int cc0 = c - 1 - g;
        const unsigned long long* base = agg + (size_t)b * NCH * cF + fidx;
        unsigned long long vv[4];
#pragma unroll
        for (int s2 = 0; s2 < 4; ++s2) {
            int cc = cc0 - 4 * s2;
            vv[s2] = (cc > lastc) ? agg_ld(base + (size_t)cc * cF) : 0ull;
        }

        // ---- in-chunk inclusive cumsum (serial VALU; hides walk latency) ----
        {
            float cK = 0.f, cV = 0.f;
#pragma unroll
            for (int mm = 0; mm < 4; ++mm) {
                f32x4 aK = accK[mm], aV = accV[mm];
                aK[1] += aK[0]; aK[2] += aK[1]; aK[3] += aK[2];
                aV[1] += aV[0]; aV[2] += aV[1]; aV[3] += aV[2];
                float tK = aK[3], tV = aV[3];
                float uK = __shfl_up(tK, 16), uV = __shfl_up(tV, 16);
                if (g >= 1) { tK += uK; tV += uV; }
                float xK = __shfl_up(tK, 32), xV = __shfl_up(tV, 32);
                if (g >= 2) { tK += xK; tV += xV; }
                float eK = tK - aK[3] + cK;
                float eV = tV - aV[3] + cV;
                aK[0] += eK; aK[1] += eK; aK[2] += eK; aK[3] += eK;
                aV[0] += eV; aV[1] += eV; aV[2] += eV; aV[3] += eV;
                accK[mm] = aK; accV[mm] = aV;
                cK += __shfl(tK, 48 + col);
                cV += __shfl(tV, 48 + col);
            }
        }

        // ---- finish walk: check/retry (rare), fixed xor-tree combine ----
        {
            float dk = 0.f, dv = 0.f;
#pragma unroll
            for (int s2 = 0; s2 < 4; ++s2) {
                int cc = cc0 - 4 * s2;
                if (cc > lastc) {
                    unsigned long long v0 = vv[s2];
                    while ((unsigned)v0 == 0u) v0 = agg_ld(base + (size_t)cc * cF);
                    dk += __uint_as_float((unsigned)v0) - 1.0f;
                    dv += __uint_as_float((unsigned)(v0 >> 32));
                }
            }
            dk += __shfl_xor(dk, 16);
            dk += __shfl_xor(dk, 32);
            dv += __shfl_xor(dv, 16);
            dv += __shfl_xor(dv, 32);
            carK += dk;            // now = prefix through c-1
            carV += dv;
        }

        // ---- attn in place: accV := attn (accK dead after) ----
#pragma unroll
        for (int mm = 0; mm < 4; ++mm)
#pragma unroll
            for (int r = 0; r < 4; ++r) {
                float kc = accK[mm][r] + carK;
                float vc = accV[mm][r] + carV;
                accV[mm][r] = __fdividef(vc + EPS_, kc + EPS_);
            }
        carK += ktot;              // prefix through c (incl own chunk)
        carV += kvtot;

        // ---- Q feature GEMM + output ----
        f32x4 accQ[4] = {};
        gemm_pass(afQ, wsplit, w, l, accQ);

        const size_t obase = ((size_t)b * cS + (size_t)c * CHUNK) * cF;
#pragma unroll
        for (int mm = 0; mm < 4; ++mm)
#pragma unroll
            for (int r = 0; r < 4; ++r) {
                int s = mm * 16 + g * 4 + r;
                float qf = accQ[mm][r];
                float qs = (qf > 0.5f) ? qf : 0.f;
                out[obase + (size_t)s * cF + fidx] = qs * accV[mm][r];
            }
    }
}

// ---------------------------------------------------------------------------
extern "C" void kernel_launch(void* const* d_in, const int* in_sizes, int n_in,
                              void* d_out, int out_size, void* d_ws, size_t ws_size,
                              hipStream_t stream) {
    const float* q = (const float*)d_in[0];
    const float* k = (const float*)d_in[1];
    const float* v = (const float*)d_in[2];
    const float* w = (const float*)d_in[3];
    float* out = (float*)d_out;

    unsigned short* wsplit = (unsigned short*)d_ws;                       // 48 KiB
    unsigned long long* agg = (unsigned long long*)((char*)d_ws + 65536); // 4 MiB

    hipMemsetAsync(agg, 0, (size_t)cB * NCH * cF * sizeof(unsigned long long), stream);
    k_wsplit<<<1, 256, 0, stream>>>(w, wsplit);
    k_main<<<cB * BPB, THR, 0, stream>>>(q, k, v, wsplit, out, agg);
}

// Round 20
// 129.338 us; speedup vs baseline: 1.7181x; 1.0774x over previous
//
#include <hip/hip_runtime.h>

// SpikingLinearAttention forward — fused chunk-scan kernel, v17.
//  = v13 (R15/R19: 137.7/139.3us, best measured & reproduced) + two zero-risk
//    residual cuts (no structure/register/math change):
//  (a) s_setprio(1) around GEMM passes (T5): 2 independent blocks/CU run at
//      skewed phases (walk/spin timing), so the CU scheduler can favor the
//      MFMA-cluster wave over the co-resident block's staging/poll traffic
//      (m191-style diversity; scalar instr, no codegen impact).
//  (b) k_wsplit parallelized 1 -> 32 blocks (was a serial ~5-10us prologue
//      with scattered ushort stores; now 1 elem/thread).
//  Carried verbatim from v13: 512 blocks (16/batch, 8 chunks each, stride 16,
//  in-register carry), 8 waves, 3 af LDS buffers (75KB), 2 barriers/iter,
//  merged K/V GEMM (8 chains), XCD-grouped mapping, 6-term bf16-split MFMA
//  (f32-dot precision), f32 gate, in-register in-chunk cumsum (MFMA C/D
//  layout), deterministic decoupled lookback (8B agent atomics).
//  Constraint surface mapped R7-R18: 16 waves/CU hard floor; 3-acc overlap
//  spills; per-iter rendezvous ~free; prefetch-at-staging optimal.

constexpr int cB = 32;
constexpr int cS = 8192;
constexpr int cD = 64;
constexpr int cF = 128;
constexpr int CHUNK = 64;
constexpr int NCH = cS / CHUNK;   // 128 chunks per batch
constexpr int SLOT = 520;         // ushorts per p-plane slot (1040 B)
constexpr int THR = 512;          // 8 waves
constexpr int BPB = 16;           // blocks per batch
constexpr int ITERS = NCH / BPB;  // 8 chunks per block, stride BPB
constexpr float EPS_ = 1e-8f;

typedef __attribute__((ext_vector_type(8))) short bf16x8;  // 8 bf16 (4 VGPRs)
typedef __attribute__((ext_vector_type(4))) float f32x4;   // 4 f32 acc

#define MFMA16(a, b, c) __builtin_amdgcn_mfma_f32_16x16x32_bf16((a), (b), (c), 0, 0, 0)

// ---- bf16 helpers ----------------------------------------------------------
__device__ __forceinline__ unsigned short bf16rn(float x) {
    unsigned u = __float_as_uint(x);
    unsigned r = u + 0x7FFFu + ((u >> 16) & 1u);
    return (unsigned short)(r >> 16);
}
__device__ __forceinline__ float bf16tof(unsigned short h) {
    return __uint_as_float((unsigned)h << 16);
}
__device__ __forceinline__ void split3(float x, unsigned short& a0,
                                       unsigned short& a1, unsigned short& a2) {
    a0 = bf16rn(x);
    float r1 = x - bf16tof(a0);
    a1 = bf16rn(r1);
    float r2 = r1 - bf16tof(a1);
    a2 = bf16rn(r2);
}
// packed RNE bf16 pair (same rounding as bf16rn -> numerically identical)
__device__ __forceinline__ unsigned cvtpk(float lo, float hi) {
    unsigned r;
    asm("v_cvt_pk_bf16_f32 %0, %1, %2" : "=v"(r) : "v"(lo), "v"(hi));
    return r;
}
__device__ __forceinline__ float unpk_lo(unsigned u) {
    return __uint_as_float(u << 16);
}
__device__ __forceinline__ float unpk_hi(unsigned u) {
    return __uint_as_float(u & 0xFFFF0000u);
}

// A-frag: lane l holds A[l&15][(l>>4)*8+j].  B-frag: lane l holds B[(l>>4)*8+j][l&15].
// C/D: lane l, reg r -> row (l>>4)*4+r, col l&15.  [m89-verified, carried]

// ---- K0: split W (64x128) into 3 bf16 matrices in B-frag order (global) ----
// 32 blocks x 256 threads, one element each (was 1 block, serial ~32/thread).
__global__ __launch_bounds__(256) void k_wsplit(const float* __restrict__ W,
                                                unsigned short* __restrict__ ws) {
    int i = blockIdx.x * 256 + threadIdx.x;
    if (i < cD * cF) {
        int d = i >> 7, f = i & 127;
        unsigned short s0, s1, s2;
        split3(W[i], s0, s1, s2);
        int n = f >> 4, k = d >> 5;
        int lane = (f & 15) | (((d >> 3) & 3) << 4);
        int j = d & 7;
        int base = ((n * 2 + k) * 3) * 512 + lane * 8 + j;
        ws[base]        = s0;
        ws[base + 512]  = s1;
        ws[base + 1024] = s2;
    }
}

// ---- staging transform: exp + cvt_pk split + swizzled frag-order store -----
// in-slot byte b0 = lane_frag*16 + jj*8 ; stored at b0 ^ (((b0>>8)&3)<<5).
__device__ __forceinline__ void transform_store(float4 a, int idx,
                                                unsigned short* __restrict__ af) {
    int row = idx >> 4, c4 = (idx & 15) * 4;
    float e0 = __expf(a.x), e1 = __expf(a.y), e2 = __expf(a.z), e3 = __expf(a.w);
    uint2 v0;
    v0.x = cvtpk(e0, e1);
    v0.y = cvtpk(e2, e3);
    float r0 = e0 - unpk_lo(v0.x), r1 = e1 - unpk_hi(v0.x);
    float r2 = e2 - unpk_lo(v0.y), r3 = e3 - unpk_hi(v0.y);
    uint2 v1;
    v1.x = cvtpk(r0, r1);
    v1.y = cvtpk(r2, r3);
    float t0 = r0 - unpk_lo(v1.x), t1 = r1 - unpk_hi(v1.x);
    float t2 = r2 - unpk_lo(v1.y), t3 = r3 - unpk_hi(v1.y);
    uint2 v2;
    v2.x = cvtpk(t0, t1);
    v2.y = cvtpk(t2, t3);

    int m = row >> 4, k = c4 >> 5;
    int lane_frag = (row & 15) | (((c4 >> 3) & 3) << 4);
    int jj = (c4 & 7) >> 2;
    int b0 = lane_frag * 16 + jj * 8;
    int byte = b0 ^ (((b0 >> 8) & 3) << 5);
    char* dst = (char*)af + (m * 2 + k) * 3 * (SLOT * 2) + byte;
    *(uint2*)(dst)            = v0;
    *(uint2*)(dst + SLOT * 2) = v1;
    *(uint2*)(dst + SLOT * 4) = v2;
}

__device__ __forceinline__ void load_mat(const float4* __restrict__ src, int t,
                                         float4 ld[2]) {
#pragma unroll
    for (int i = 0; i < 2; ++i) ld[i] = src[t + i * THR];
}
__device__ __forceinline__ void write_mat(const float4 ld[2],
                                          unsigned short* __restrict__ af, int t) {
    transform_store(ld[0], t, af);
    transform_store(ld[1], t + THR, af);
}

__device__ __forceinline__ void read_frag(const unsigned short* __restrict__ af,
                                          int mk, int l, bf16x8* out3) {
    int b0 = l * 16;
    int byte = b0 ^ (((b0 >> 8) & 3) << 5);
    const char* p = (const char*)af + mk * 3 * (SLOT * 2) + byte;
    out3[0] = *(const bf16x8*)(p);
    out3[1] = *(const bf16x8*)(p + SLOT * 2);
    out3[2] = *(const bf16x8*)(p + SLOT * 4);
}

#define GEMM6(acc, A, Wf)            \
    acc = MFMA16(A[0], Wf[0], acc);  \
    acc = MFMA16(A[0], Wf[1], acc);  \
    acc = MFMA16(A[1], Wf[0], acc);  \
    acc = MFMA16(A[1], Wf[1], acc);  \
    acc = MFMA16(A[0], Wf[2], acc);  \
    acc = MFMA16(A[2], Wf[0], acc);

// single-matrix GEMM (used for Q): wave w owns n-tile n=w.  T5: high wave
// priority across the ds_read+MFMA cluster (2 blocks/CU at skewed phases).
__device__ __forceinline__ void gemm_pass(const unsigned short* __restrict__ af,
                                          const unsigned short* __restrict__ wsplit,
                                          int w, int l, f32x4 acc[4]) {
    __builtin_amdgcn_s_setprio(1);
#pragma unroll
    for (int k = 0; k < 2; ++k) {
        bf16x8 wf[3];
#pragma unroll
        for (int p = 0; p < 3; ++p)
            wf[p] = *(const bf16x8*)(wsplit + (size_t)((((w * 2 + k) * 3 + p) * 512) + l * 8));
#pragma unroll
        for (int m = 0; m < 4; ++m) {
            bf16x8 a[3];
            read_frag(af, m * 2 + k, l, a);
            GEMM6(acc[m], a, wf);
        }
    }
    __builtin_amdgcn_s_setprio(0);
}

// merged K+V GEMM: 8 independent accumulator chains, shared W-frags,
// one ds_read pair per sub-tile feeds two GEMM6 clusters.
__device__ __forceinline__ void gemm_pass2(const unsigned short* __restrict__ afK,
                                           const unsigned short* __restrict__ afV,
                                           const unsigned short* __restrict__ wsplit,
                                           int w, int l,
                                           f32x4 accK[4], f32x4 accV[4]) {
    __builtin_amdgcn_s_setprio(1);
#pragma unroll
    for (int k = 0; k < 2; ++k) {
        bf16x8 wf[3];
#pragma unroll
        for (int p = 0; p < 3; ++p)
            wf[p] = *(const bf16x8*)(wsplit + (size_t)((((w * 2 + k) * 3 + p) * 512) + l * 8));
#pragma unroll
        for (int m = 0; m < 4; ++m) {
            bf16x8 aK[3], aV[3];
            read_frag(afK, m * 2 + k, l, aK);
            read_frag(afV, m * 2 + k, l, aV);
            GEMM6(accK[m], aK, wf);
            GEMM6(accV[m], aV, wf);
        }
    }
    __builtin_amdgcn_s_setprio(0);
}

__device__ __forceinline__ unsigned long long agg_ld(const unsigned long long* p) {
    return __hip_atomic_load(p, __ATOMIC_RELAXED, __HIP_MEMORY_SCOPE_AGENT);
}

// ---- fused kernel ----------------------------------------------------------
__global__ __launch_bounds__(THR, 4) void k_main(const float* __restrict__ Q,
                                                 const float* __restrict__ K,
                                                 const float* __restrict__ V,
                                                 const unsigned short* __restrict__ wsplit,
                                                 float* __restrict__ out,
                                                 unsigned long long* __restrict__ agg)
{
    __shared__ unsigned short afK[24 * SLOT];   // 24960 B each, 74880 total
    __shared__ unsigned short afV[24 * SLOT];
    __shared__ unsigned short afQ[24 * SLOT];

    // XCD-grouped: all 16 blocks of batch b land on XCD b%8 (i = m*32 + b,
    // 32 == 0 mod 8); predecessors (smaller m) have smaller linear id.
    const int i0 = blockIdx.x;
    const int b = i0 & 31, m = i0 >> 5;          // 16 blocks per batch
    const int t = threadIdx.x, w = t >> 6, l = t & 63;
    const int col = l & 15, g = l >> 4;
    const int fidx = w * 16 + col;

    // prologue: load chunk m
    float4 ldK[2], ldV[2], ldQ[2];
    {
        const size_t rb = ((size_t)b * cS + (size_t)m * CHUNK) * cD;
        load_mat((const float4*)(K + rb), t, ldK);
        load_mat((const float4*)(V + rb), t, ldV);
        load_mat((const float4*)(Q + rb), t, ldQ);
    }
    float carK = 0.f, carV = 0.f;   // prefix through previous own chunk (incl)

    for (int j = 0; j < ITERS; ++j) {
        const int c = j * BPB + m;

        // ---- stage current chunk; issue next chunk's loads ----
        __syncthreads();                       // af free (prev iter reads done)
        write_mat(ldK, afK, t);
        write_mat(ldV, afV, t);
        write_mat(ldQ, afQ, t);
        if (j + 1 < ITERS) {
            const size_t rb = ((size_t)b * cS + (size_t)(c + BPB) * CHUNK) * cD;
            load_mat((const float4*)(K + rb), t, ldK);
            load_mat((const float4*)(V + rb), t, ldV);
            load_mat((const float4*)(Q + rb), t, ldQ);
        }
        __syncthreads();                       // af ready

        // ---- K and V feature GEMMs (merged, 8 independent chains) ----
        f32x4 accK[4] = {};
        f32x4 accV[4] = {};
        gemm_pass2(afK, afV, wsplit, w, l, accK, accV);

        // ---- gate: accK := k_s, accV := k_s * v_f ----
#pragma unroll
        for (int mm = 0; mm < 4; ++mm)
#pragma unroll
            for (int r = 0; r < 4; ++r) {
                float kf = accK[mm][r];
                float ks = (kf > 0.5f) ? kf : 0.f;
                accK[mm][r] = ks;
                accV[mm][r] = ks * accV[mm][r];
            }

        // ---- fast chunk totals (fixed xor tree) + publish ASAP ----
        float ktot = 0.f, kvtot = 0.f;
#pragma unroll
        for (int mm = 0; mm < 4; ++mm)
#pragma unroll
            for (int r = 0; r < 4; ++r) {
                ktot += accK[mm][r];
                kvtot += accV[mm][r];
            }
        ktot += __shfl_xor(ktot, 16);
        ktot += __shfl_xor(ktot, 32);
        kvtot += __shfl_xor(kvtot, 16);
        kvtot += __shfl_xor(kvtot, 32);
        if (g == 0) {
            unsigned long long u = ((unsigned long long)__float_as_uint(kvtot) << 32)
                                 | (unsigned long long)__float_as_uint(ktot + 1.0f);
            __hip_atomic_store(agg + (size_t)(b * NCH + c) * cF + fidx, u,
                               __ATOMIC_RELAXED, __HIP_MEMORY_SCOPE_AGENT);
        }

        // ---- issue walk loads (<=4/lane, independent) before cumsum ----
        const int lastc = (j == 0) ? -1 : (c - BPB);
        const int cc0 = c - 1 - g;
        const unsigned long long* base = agg + (size_t)b * NCH * cF + fidx;
        unsigned long long vv[4];
#pragma unroll
        for (int s2 = 0; s2 < 4; ++s2) {
            int cc = cc0 - 4 * s2;
            vv[s2] = (cc > lastc) ? agg_ld(base + (size_t)cc * cF) : 0ull;
        }

        // ---- in-chunk inclusive cumsum (serial VALU; hides walk latency) ----
        {
            float cK = 0.f, cV = 0.f;
#pragma unroll
            for (int mm = 0; mm < 4; ++mm) {
                f32x4 aK = accK[mm], aV = accV[mm];
                aK[1] += aK[0]; aK[2] += aK[1]; aK[3] += aK[2];
                aV[1] += aV[0]; aV[2] += aV[1]; aV[3] += aV[2];
                float tK = aK[3], tV = aV[3];
                float uK = __shfl_up(tK, 16), uV = __shfl_up(tV, 16);
                if (g >= 1) { tK += uK; tV += uV; }
                float xK = __shfl_up(tK, 32), xV = __shfl_up(tV, 32);
                if (g >= 2) { tK += xK; tV += xV; }
                float eK = tK - aK[3] + cK;
                float eV = tV - aV[3] + cV;
                aK[0] += eK; aK[1] += eK; aK[2] += eK; aK[3] += eK;
                aV[0] += eV; aV[1] += eV; aV[2] += eV; aV[3] += eV;
                accK[mm] = aK; accV[mm] = aV;
                cK += __shfl(tK, 48 + col);
                cV += __shfl(tV, 48 + col);
            }
        }

        // ---- finish walk: check/retry (rare), fixed xor-tree combine ----
        {
            float dk = 0.f, dv = 0.f;
#pragma unroll
            for (int s2 = 0; s2 < 4; ++s2) {
                int cc = cc0 - 4 * s2;
                if (cc > lastc) {
                    unsigned long long v0 = vv[s2];
                    while ((unsigned)v0 == 0u) v0 = agg_ld(base + (size_t)cc * cF);
                    dk += __uint_as_float((unsigned)v0) - 1.0f;
                    dv += __uint_as_float((unsigned)(v0 >> 32));
                }
            }
            dk += __shfl_xor(dk, 16);
            dk += __shfl_xor(dk, 32);
            dv += __shfl_xor(dv, 16);
            dv += __shfl_xor(dv, 32);
            carK += dk;            // now = prefix through c-1
            carV += dv;
        }

        // ---- attn in place: accV := attn (accK dead after) ----
#pragma unroll
        for (int mm = 0; mm < 4; ++mm)
#pragma unroll
            for (int r = 0; r < 4; ++r) {
                float kc = accK[mm][r] + carK;
                float vc = accV[mm][r] + carV;
                accV[mm][r] = __fdividef(vc + EPS_, kc + EPS_);
            }
        carK += ktot;              // prefix through c (incl own chunk)
        carV += kvtot;

        // ---- Q feature GEMM + output ----
        f32x4 accQ[4] = {};
        gemm_pass(afQ, wsplit, w, l, accQ);

        const size_t obase = ((size_t)b * cS + (size_t)c * CHUNK) * cF;
#pragma unroll
        for (int mm = 0; mm < 4; ++mm)
#pragma unroll
            for (int r = 0; r < 4; ++r) {
                int s = mm * 16 + g * 4 + r;
                float qf = accQ[mm][r];
                float qs = (qf > 0.5f) ? qf : 0.f;
                out[obase + (size_t)s * cF + fidx] = qs * accV[mm][r];
            }
    }
}

// ---------------------------------------------------------------------------
extern "C" void kernel_launch(void* const* d_in, const int* in_sizes, int n_in,
                              void* d_out, int out_size, void* d_ws, size_t ws_size,
                              hipStream_t stream) {
    const float* q = (const float*)d_in[0];
    const float* k = (const float*)d_in[1];
    const float* v = (const float*)d_in[2];
    const float* w = (const float*)d_in[3];
    float* out = (float*)d_out;

    unsigned short* wsplit = (unsigned short*)d_ws;                       // 48 KiB
    unsigned long long* agg = (unsigned long long*)((char*)d_ws + 65536); // 4 MiB

    hipMemsetAsync(agg, 0, (size_t)cB * NCH * cF * sizeof(unsigned long long), stream);
    k_wsplit<<<32, 256, 0, stream>>>(w, wsplit);
    k_main<<<cB * BPB, THR, 0, stream>>>(q, k, v, wsplit, out, agg);
}

// Round 21
// 126.494 us; speedup vs baseline: 1.7567x; 1.0225x over previous
//
#include <hip/hip_runtime.h>

// SpikingLinearAttention forward — fused chunk-scan kernel, v18.
//  = v17 (R20: 129.3us, best) + two scheduling/overhead cuts:
//  (a) agg-table zeroing folded into k_wsplit (one fewer graph dispatch;
//      stream order still guarantees zeroed-before-k_main).
//  (b) setprio(1) extended to the in-chunk cumsum — a serial shfl/VALU chain
//      on the block critical path; priority wins issue slots vs the
//      co-resident block's latency-tolerant staging (same mechanism as the
//      GEMM setprio win in R20 / m191).
//  Carried verbatim from v17/v13: 512 blocks (16/batch, 8 chunks each,
//  stride 16, in-register carry), 8 waves, 3 af LDS buffers (75KB),
//  2 barriers/iter, merged K/V GEMM (8 chains), XCD-grouped mapping,
//  6-term bf16-split MFMA (f32-dot precision), f32 gate, in-register
//  in-chunk cumsum (MFMA C/D layout), deterministic decoupled lookback.
//  Constraint surface (R7-R18): 16 waves/CU hard floor; 3-acc overlap
//  spills; per-iter rendezvous ~free; prefetch-at-staging optimal.

constexpr int cB = 32;
constexpr int cS = 8192;
constexpr int cD = 64;
constexpr int cF = 128;
constexpr int CHUNK = 64;
constexpr int NCH = cS / CHUNK;   // 128 chunks per batch
constexpr int SLOT = 520;         // ushorts per p-plane slot (1040 B)
constexpr int THR = 512;          // 8 waves
constexpr int BPB = 16;           // blocks per batch
constexpr int ITERS = NCH / BPB;  // 8 chunks per block, stride BPB
constexpr float EPS_ = 1e-8f;

typedef __attribute__((ext_vector_type(8))) short bf16x8;  // 8 bf16 (4 VGPRs)
typedef __attribute__((ext_vector_type(4))) float f32x4;   // 4 f32 acc

#define MFMA16(a, b, c) __builtin_amdgcn_mfma_f32_16x16x32_bf16((a), (b), (c), 0, 0, 0)

// ---- bf16 helpers ----------------------------------------------------------
__device__ __forceinline__ unsigned short bf16rn(float x) {
    unsigned u = __float_as_uint(x);
    unsigned r = u + 0x7FFFu + ((u >> 16) & 1u);
    return (unsigned short)(r >> 16);
}
__device__ __forceinline__ float bf16tof(unsigned short h) {
    return __uint_as_float((unsigned)h << 16);
}
__device__ __forceinline__ void split3(float x, unsigned short& a0,
                                       unsigned short& a1, unsigned short& a2) {
    a0 = bf16rn(x);
    float r1 = x - bf16tof(a0);
    a1 = bf16rn(r1);
    float r2 = r1 - bf16tof(a1);
    a2 = bf16rn(r2);
}
// packed RNE bf16 pair (same rounding as bf16rn -> numerically identical)
__device__ __forceinline__ unsigned cvtpk(float lo, float hi) {
    unsigned r;
    asm("v_cvt_pk_bf16_f32 %0, %1, %2" : "=v"(r) : "v"(lo), "v"(hi));
    return r;
}
__device__ __forceinline__ float unpk_lo(unsigned u) {
    return __uint_as_float(u << 16);
}
__device__ __forceinline__ float unpk_hi(unsigned u) {
    return __uint_as_float(u & 0xFFFF0000u);
}

// A-frag: lane l holds A[l&15][(l>>4)*8+j].  B-frag: lane l holds B[(l>>4)*8+j][l&15].
// C/D: lane l, reg r -> row (l>>4)*4+r, col l&15.  [m89-verified, carried]

// ---- K0: split W into B-frag order + zero the agg table --------------------
// 32 blocks x 256 threads. Also zeroes agg (4 MiB): replaces hipMemsetAsync.
__global__ __launch_bounds__(256) void k_wsplit(const float* __restrict__ W,
                                                unsigned short* __restrict__ ws,
                                                unsigned long long* __restrict__ agg) {
    int i = blockIdx.x * 256 + threadIdx.x;
    if (i < cD * cF) {
        int d = i >> 7, f = i & 127;
        unsigned short s0, s1, s2;
        split3(W[i], s0, s1, s2);
        int n = f >> 4, k = d >> 5;
        int lane = (f & 15) | (((d >> 3) & 3) << 4);
        int j = d & 7;
        int base = ((n * 2 + k) * 3) * 512 + lane * 8 + j;
        ws[base]        = s0;
        ws[base + 512]  = s1;
        ws[base + 1024] = s2;
    }
    // zero agg: 32*128*128 = 524288 u64 over 8192 threads = 64 each
    const int NA = cB * NCH * cF;
    for (int a = i; a < NA; a += 32 * 256)
        agg[a] = 0ull;
}

// ---- staging transform: exp + cvt_pk split + swizzled frag-order store -----
// in-slot byte b0 = lane_frag*16 + jj*8 ; stored at b0 ^ (((b0>>8)&3)<<5).
__device__ __forceinline__ void transform_store(float4 a, int idx,
                                                unsigned short* __restrict__ af) {
    int row = idx >> 4, c4 = (idx & 15) * 4;
    float e0 = __expf(a.x), e1 = __expf(a.y), e2 = __expf(a.z), e3 = __expf(a.w);
    uint2 v0;
    v0.x = cvtpk(e0, e1);
    v0.y = cvtpk(e2, e3);
    float r0 = e0 - unpk_lo(v0.x), r1 = e1 - unpk_hi(v0.x);
    float r2 = e2 - unpk_lo(v0.y), r3 = e3 - unpk_hi(v0.y);
    uint2 v1;
    v1.x = cvtpk(r0, r1);
    v1.y = cvtpk(r2, r3);
    float t0 = r0 - unpk_lo(v1.x), t1 = r1 - unpk_hi(v1.x);
    float t2 = r2 - unpk_lo(v1.y), t3 = r3 - unpk_hi(v1.y);
    uint2 v2;
    v2.x = cvtpk(t0, t1);
    v2.y = cvtpk(t2, t3);

    int m = row >> 4, k = c4 >> 5;
    int lane_frag = (row & 15) | (((c4 >> 3) & 3) << 4);
    int jj = (c4 & 7) >> 2;
    int b0 = lane_frag * 16 + jj * 8;
    int byte = b0 ^ (((b0 >> 8) & 3) << 5);
    char* dst = (char*)af + (m * 2 + k) * 3 * (SLOT * 2) + byte;
    *(uint2*)(dst)            = v0;
    *(uint2*)(dst + SLOT * 2) = v1;
    *(uint2*)(dst + SLOT * 4) = v2;
}

__device__ __forceinline__ void load_mat(const float4* __restrict__ src, int t,
                                         float4 ld[2]) {
#pragma unroll
    for (int i = 0; i < 2; ++i) ld[i] = src[t + i * THR];
}
__device__ __forceinline__ void write_mat(const float4 ld[2],
                                          unsigned short* __restrict__ af, int t) {
    transform_store(ld[0], t, af);
    transform_store(ld[1], t + THR, af);
}

__device__ __forceinline__ void read_frag(const unsigned short* __restrict__ af,
                                          int mk, int l, bf16x8* out3) {
    int b0 = l * 16;
    int byte = b0 ^ (((b0 >> 8) & 3) << 5);
    const char* p = (const char*)af + mk * 3 * (SLOT * 2) + byte;
    out3[0] = *(const bf16x8*)(p);
    out3[1] = *(const bf16x8*)(p + SLOT * 2);
    out3[2] = *(const bf16x8*)(p + SLOT * 4);
}

#define GEMM6(acc, A, Wf)            \
    acc = MFMA16(A[0], Wf[0], acc);  \
    acc = MFMA16(A[0], Wf[1], acc);  \
    acc = MFMA16(A[1], Wf[0], acc);  \
    acc = MFMA16(A[1], Wf[1], acc);  \
    acc = MFMA16(A[0], Wf[2], acc);  \
    acc = MFMA16(A[2], Wf[0], acc);

// single-matrix GEMM (used for Q): wave w owns n-tile n=w.  T5: high wave
// priority across the ds_read+MFMA cluster (2 blocks/CU at skewed phases).
__device__ __forceinline__ void gemm_pass(const unsigned short* __restrict__ af,
                                          const unsigned short* __restrict__ wsplit,
                                          int w, int l, f32x4 acc[4]) {
    __builtin_amdgcn_s_setprio(1);
#pragma unroll
    for (int k = 0; k < 2; ++k) {
        bf16x8 wf[3];
#pragma unroll
        for (int p = 0; p < 3; ++p)
            wf[p] = *(const bf16x8*)(wsplit + (size_t)((((w * 2 + k) * 3 + p) * 512) + l * 8));
#pragma unroll
        for (int m = 0; m < 4; ++m) {
            bf16x8 a[3];
            read_frag(af, m * 2 + k, l, a);
            GEMM6(acc[m], a, wf);
        }
    }
    __builtin_amdgcn_s_setprio(0);
}

// merged K+V GEMM: 8 independent accumulator chains, shared W-frags,
// one ds_read pair per sub-tile feeds two GEMM6 clusters.
__device__ __forceinline__ void gemm_pass2(const unsigned short* __restrict__ afK,
                                           const unsigned short* __restrict__ afV,
                                           const unsigned short* __restrict__ wsplit,
                                           int w, int l,
                                           f32x4 accK[4], f32x4 accV[4]) {
    __builtin_amdgcn_s_setprio(1);
#pragma unroll
    for (int k = 0; k < 2; ++k) {
        bf16x8 wf[3];
#pragma unroll
        for (int p = 0; p < 3; ++p)
            wf[p] = *(const bf16x8*)(wsplit + (size_t)((((w * 2 + k) * 3 + p) * 512) + l * 8));
#pragma unroll
        for (int m = 0; m < 4; ++m) {
            bf16x8 aK[3], aV[3];
            read_frag(afK, m * 2 + k, l, aK);
            read_frag(afV, m * 2 + k, l, aV);
            GEMM6(accK[m], aK, wf);
            GEMM6(accV[m], aV, wf);
        }
    }
    __builtin_amdgcn_s_setprio(0);
}

__device__ __forceinline__ unsigned long long agg_ld(const unsigned long long* p) {
    return __hip_atomic_load(p, __ATOMIC_RELAXED, __HIP_MEMORY_SCOPE_AGENT);
}

// ---- fused kernel ----------------------------------------------------------
__global__ __launch_bounds__(THR, 4) void k_main(const float* __restrict__ Q,
                                                 const float* __restrict__ K,
                                                 const float* __restrict__ V,
                                                 const unsigned short* __restrict__ wsplit,
                                                 float* __restrict__ out,
                                                 unsigned long long* __restrict__ agg)
{
    __shared__ unsigned short afK[24 * SLOT];   // 24960 B each, 74880 total
    __shared__ unsigned short afV[24 * SLOT];
    __shared__ unsigned short afQ[24 * SLOT];

    // XCD-grouped: all 16 blocks of batch b land on XCD b%8 (i = m*32 + b,
    // 32 == 0 mod 8); predecessors (smaller m) have smaller linear id.
    const int i0 = blockIdx.x;
    const int b = i0 & 31, m = i0 >> 5;          // 16 blocks per batch
    const int t = threadIdx.x, w = t >> 6, l = t & 63;
    const int col = l & 15, g = l >> 4;
    const int fidx = w * 16 + col;

    // prologue: load chunk m
    float4 ldK[2], ldV[2], ldQ[2];
    {
        const size_t rb = ((size_t)b * cS + (size_t)m * CHUNK) * cD;
        load_mat((const float4*)(K + rb), t, ldK);
        load_mat((const float4*)(V + rb), t, ldV);
        load_mat((const float4*)(Q + rb), t, ldQ);
    }
    float carK = 0.f, carV = 0.f;   // prefix through previous own chunk (incl)

    for (int j = 0; j < ITERS; ++j) {
        const int c = j * BPB + m;

        // ---- stage current chunk; issue next chunk's loads ----
        __syncthreads();                       // af free (prev iter reads done)
        write_mat(ldK, afK, t);
        write_mat(ldV, afV, t);
        write_mat(ldQ, afQ, t);
        if (j + 1 < ITERS) {
            const size_t rb = ((size_t)b * cS + (size_t)(c + BPB) * CHUNK) * cD;
            load_mat((const float4*)(K + rb), t, ldK);
            load_mat((const float4*)(V + rb), t, ldV);
            load_mat((const float4*)(Q + rb), t, ldQ);
        }
        __syncthreads();                       // af ready

        // ---- K and V feature GEMMs (merged, 8 independent chains) ----
        f32x4 accK[4] = {};
        f32x4 accV[4] = {};
        gemm_pass2(afK, afV, wsplit, w, l, accK, accV);

        // ---- gate: accK := k_s, accV := k_s * v_f ----
#pragma unroll
        for (int mm = 0; mm < 4; ++mm)
#pragma unroll
            for (int r = 0; r < 4; ++r) {
                float kf = accK[mm][r];
                float ks = (kf > 0.5f) ? kf : 0.f;
                accK[mm][r] = ks;
                accV[mm][r] = ks * accV[mm][r];
            }

        // ---- fast chunk totals (fixed xor tree) + publish ASAP ----
        float ktot = 0.f, kvtot = 0.f;
#pragma unroll
        for (int mm = 0; mm < 4; ++mm)
#pragma unroll
            for (int r = 0; r < 4; ++r) {
                ktot += accK[mm][r];
                kvtot += accV[mm][r];
            }
        ktot += __shfl_xor(ktot, 16);
        ktot += __shfl_xor(ktot, 32);
        kvtot += __shfl_xor(kvtot, 16);
        kvtot += __shfl_xor(kvtot, 32);
        if (g == 0) {
            unsigned long long u = ((unsigned long long)__float_as_uint(kvtot) << 32)
                                 | (unsigned long long)__float_as_uint(ktot + 1.0f);
            __hip_atomic_store(agg + (size_t)(b * NCH + c) * cF + fidx, u,
                               __ATOMIC_RELAXED, __HIP_MEMORY_SCOPE_AGENT);
        }

        // ---- issue walk loads (<=4/lane, independent) before cumsum ----
        const int lastc = (j == 0) ? -1 : (c - BPB);
        const int cc0 = c - 1 - g;
        const unsigned long long* base = agg + (size_t)b * NCH * cF + fidx;
        unsigned long long vv[4];
#pragma unroll
        for (int s2 = 0; s2 < 4; ++s2) {
            int cc = cc0 - 4 * s2;
            vv[s2] = (cc > lastc) ? agg_ld(base + (size_t)cc * cF) : 0ull;
        }

        // ---- in-chunk inclusive cumsum (serial VALU chain on critical path;
        //      prioritized vs co-resident block's staging) ----
        __builtin_amdgcn_s_setprio(1);
        {
            float cK = 0.f, cV = 0.f;
#pragma unroll
            for (int mm = 0; mm < 4; ++mm) {
                f32x4 aK = accK[mm], aV = accV[mm];
                aK[1] += aK[0]; aK[2] += aK[1]; aK[3] += aK[2];
                aV[1] += aV[0]; aV[2] += aV[1]; aV[3] += aV[2];
                float tK = aK[3], tV = aV[3];
                float uK = __shfl_up(tK, 16), uV = __shfl_up(tV, 16);
                if (g >= 1) { tK += uK; tV += uV; }
                float xK = __shfl_up(tK, 32), xV = __shfl_up(tV, 32);
                if (g >= 2) { tK += xK; tV += xV; }
                float eK = tK - aK[3] + cK;
                float eV = tV - aV[3] + cV;
                aK[0] += eK; aK[1] += eK; aK[2] += eK; aK[3] += eK;
                aV[0] += eV; aV[1] += eV; aV[2] += eV; aV[3] += eV;
                accK[mm] = aK; accV[mm] = aV;
                cK += __shfl(tK, 48 + col);
                cV += __shfl(tV, 48 + col);
            }
        }
        __builtin_amdgcn_s_setprio(0);

        // ---- finish walk: check/retry (rare), fixed xor-tree combine ----
        {
            float dk = 0.f, dv = 0.f;
#pragma unroll
            for (int s2 = 0; s2 < 4; ++s2) {
                int cc = cc0 - 4 * s2;
                if (cc > lastc) {
                    unsigned long long v0 = vv[s2];
                    while ((unsigned)v0 == 0u) v0 = agg_ld(base + (size_t)cc * cF);
                    dk += __uint_as_float((unsigned)v0) - 1.0f;
                    dv += __uint_as_float((unsigned)(v0 >> 32));
                }
            }
            dk += __shfl_xor(dk, 16);
            dk += __shfl_xor(dk, 32);
            dv += __shfl_xor(dv, 16);
            dv += __shfl_xor(dv, 32);
            carK += dk;            // now = prefix through c-1
            carV += dv;
        }

        // ---- attn in place: accV := attn (accK dead after) ----
#pragma unroll
        for (int mm = 0; mm < 4; ++mm)
#pragma unroll
            for (int r = 0; r < 4; ++r) {
                float kc = accK[mm][r] + carK;
                float vc = accV[mm][r] + carV;
                accV[mm][r] = __fdividef(vc + EPS_, kc + EPS_);
            }
        carK += ktot;              // prefix through c (incl own chunk)
        carV += kvtot;

        // ---- Q feature GEMM + output ----
        f32x4 accQ[4] = {};
        gemm_pass(afQ, wsplit, w, l, accQ);

        const size_t obase = ((size_t)b * cS + (size_t)c * CHUNK) * cF;
#pragma unroll
        for (int mm = 0; mm < 4; ++mm)
#pragma unroll
            for (int r = 0; r < 4; ++r) {
                int s = mm * 16 + g * 4 + r;
                float qf = accQ[mm][r];
                float qs = (qf > 0.5f) ? qf : 0.f;
                out[obase + (size_t)s * cF + fidx] = qs * accV[mm][r];
            }
    }
}

// ---------------------------------------------------------------------------
extern "C" void kernel_launch(void* const* d_in, const int* in_sizes, int n_in,
                              void* d_out, int out_size, void* d_ws, size_t ws_size,
                              hipStream_t stream) {
    const float* q = (const float*)d_in[0];
    const float* k = (const float*)d_in[1];
    const float* v = (const float*)d_in[2];
    const float* w = (const float*)d_in[3];
    float* out = (float*)d_out;

    unsigned short* wsplit = (unsigned short*)d_ws;                       // 48 KiB
    unsigned long long* agg = (unsigned long long*)((char*)d_ws + 65536); // 4 MiB

    k_wsplit<<<32, 256, 0, stream>>>(w, wsplit, agg);  // also zeroes agg
    k_main<<<cB * BPB, THR, 0, stream>>>(q, k, v, wsplit, out, agg);
}

// Round 22
// 120.970 us; speedup vs baseline: 1.8369x; 1.0457x over previous
//
#include <hip/hip_runtime.h>

// SpikingLinearAttention forward — fused chunk-scan kernel, v19.
//  = v18 (R21: 126.5us, best) + completed wave-priority schedule:
//  Two-level priorities on the 2-blocks/CU phase-skewed structure (the one
//  lever that has paid 3 rounds straight): MFMA clusters at prio 2, serial
//  VALU chains (gate/totals/publish/poll-issue/cumsum/attn) at prio 1,
//  latency-tolerant work (staging, prefetch, walk-finish SPIN, store) at 0.
//  Carried verbatim from v18: fused agg-zeroing k_wsplit (32 blocks), 512
//  blocks (16/batch, 8 chunks each, stride 16, in-register carry), 8 waves,
//  3 af LDS buffers (75KB), 2 barriers/iter, merged K/V GEMM (8 chains),
//  XCD-grouped mapping, 6-term bf16-split MFMA (f32-dot precision), f32
//  gate, in-register in-chunk cumsum (MFMA C/D layout), deterministic
//  decoupled lookback (8B agent atomics).
//  Constraint surface (R7-R18): 16 waves/CU hard floor; 3-acc overlap
//  spills; per-iter rendezvous ~free; prefetch-at-staging optimal.

constexpr int cB = 32;
constexpr int cS = 8192;
constexpr int cD = 64;
constexpr int cF = 128;
constexpr int CHUNK = 64;
constexpr int NCH = cS / CHUNK;   // 128 chunks per batch
constexpr int SLOT = 520;         // ushorts per p-plane slot (1040 B)
constexpr int THR = 512;          // 8 waves
constexpr int BPB = 16;           // blocks per batch
constexpr int ITERS = NCH / BPB;  // 8 chunks per block, stride BPB
constexpr float EPS_ = 1e-8f;

typedef __attribute__((ext_vector_type(8))) short bf16x8;  // 8 bf16 (4 VGPRs)
typedef __attribute__((ext_vector_type(4))) float f32x4;   // 4 f32 acc

#define MFMA16(a, b, c) __builtin_amdgcn_mfma_f32_16x16x32_bf16((a), (b), (c), 0, 0, 0)

// ---- bf16 helpers ----------------------------------------------------------
__device__ __forceinline__ unsigned short bf16rn(float x) {
    unsigned u = __float_as_uint(x);
    unsigned r = u + 0x7FFFu + ((u >> 16) & 1u);
    return (unsigned short)(r >> 16);
}
__device__ __forceinline__ float bf16tof(unsigned short h) {
    return __uint_as_float((unsigned)h << 16);
}
__device__ __forceinline__ void split3(float x, unsigned short& a0,
                                       unsigned short& a1, unsigned short& a2) {
    a0 = bf16rn(x);
    float r1 = x - bf16tof(a0);
    a1 = bf16rn(r1);
    float r2 = r1 - bf16tof(a1);
    a2 = bf16rn(r2);
}
// packed RNE bf16 pair (same rounding as bf16rn -> numerically identical)
__device__ __forceinline__ unsigned cvtpk(float lo, float hi) {
    unsigned r;
    asm("v_cvt_pk_bf16_f32 %0, %1, %2" : "=v"(r) : "v"(lo), "v"(hi));
    return r;
}
__device__ __forceinline__ float unpk_lo(unsigned u) {
    return __uint_as_float(u << 16);
}
__device__ __forceinline__ float unpk_hi(unsigned u) {
    return __uint_as_float(u & 0xFFFF0000u);
}

// A-frag: lane l holds A[l&15][(l>>4)*8+j].  B-frag: lane l holds B[(l>>4)*8+j][l&15].
// C/D: lane l, reg r -> row (l>>4)*4+r, col l&15.  [m89-verified, carried]

// ---- K0: split W into B-frag order + zero the agg table --------------------
// 32 blocks x 256 threads. Also zeroes agg (4 MiB): replaces hipMemsetAsync.
__global__ __launch_bounds__(256) void k_wsplit(const float* __restrict__ W,
                                                unsigned short* __restrict__ ws,
                                                unsigned long long* __restrict__ agg) {
    int i = blockIdx.x * 256 + threadIdx.x;
    if (i < cD * cF) {
        int d = i >> 7, f = i & 127;
        unsigned short s0, s1, s2;
        split3(W[i], s0, s1, s2);
        int n = f >> 4, k = d >> 5;
        int lane = (f & 15) | (((d >> 3) & 3) << 4);
        int j = d & 7;
        int base = ((n * 2 + k) * 3) * 512 + lane * 8 + j;
        ws[base]        = s0;
        ws[base + 512]  = s1;
        ws[base + 1024] = s2;
    }
    // zero agg: 32*128*128 = 524288 u64 over 8192 threads = 64 each
    const int NA = cB * NCH * cF;
    for (int a = i; a < NA; a += 32 * 256)
        agg[a] = 0ull;
}

// ---- staging transform: exp + cvt_pk split + swizzled frag-order store -----
// in-slot byte b0 = lane_frag*16 + jj*8 ; stored at b0 ^ (((b0>>8)&3)<<5).
__device__ __forceinline__ void transform_store(float4 a, int idx,
                                                unsigned short* __restrict__ af) {
    int row = idx >> 4, c4 = (idx & 15) * 4;
    float e0 = __expf(a.x), e1 = __expf(a.y), e2 = __expf(a.z), e3 = __expf(a.w);
    uint2 v0;
    v0.x = cvtpk(e0, e1);
    v0.y = cvtpk(e2, e3);
    float r0 = e0 - unpk_lo(v0.x), r1 = e1 - unpk_hi(v0.x);
    float r2 = e2 - unpk_lo(v0.y), r3 = e3 - unpk_hi(v0.y);
    uint2 v1;
    v1.x = cvtpk(r0, r1);
    v1.y = cvtpk(r2, r3);
    float t0 = r0 - unpk_lo(v1.x), t1 = r1 - unpk_hi(v1.x);
    float t2 = r2 - unpk_lo(v1.y), t3 = r3 - unpk_hi(v1.y);
    uint2 v2;
    v2.x = cvtpk(t0, t1);
    v2.y = cvtpk(t2, t3);

    int m = row >> 4, k = c4 >> 5;
    int lane_frag = (row & 15) | (((c4 >> 3) & 3) << 4);
    int jj = (c4 & 7) >> 2;
    int b0 = lane_frag * 16 + jj * 8;
    int byte = b0 ^ (((b0 >> 8) & 3) << 5);
    char* dst = (char*)af + (m * 2 + k) * 3 * (SLOT * 2) + byte;
    *(uint2*)(dst)            = v0;
    *(uint2*)(dst + SLOT * 2) = v1;
    *(uint2*)(dst + SLOT * 4) = v2;
}

__device__ __forceinline__ void load_mat(const float4* __restrict__ src, int t,
                                         float4 ld[2]) {
#pragma unroll
    for (int i = 0; i < 2; ++i) ld[i] = src[t + i * THR];
}
__device__ __forceinline__ void write_mat(const float4 ld[2],
                                          unsigned short* __restrict__ af, int t) {
    transform_store(ld[0], t, af);
    transform_store(ld[1], t + THR, af);
}

__device__ __forceinline__ void read_frag(const unsigned short* __restrict__ af,
                                          int mk, int l, bf16x8* out3) {
    int b0 = l * 16;
    int byte = b0 ^ (((b0 >> 8) & 3) << 5);
    const char* p = (const char*)af + mk * 3 * (SLOT * 2) + byte;
    out3[0] = *(const bf16x8*)(p);
    out3[1] = *(const bf16x8*)(p + SLOT * 2);
    out3[2] = *(const bf16x8*)(p + SLOT * 4);
}

#define GEMM6(acc, A, Wf)            \
    acc = MFMA16(A[0], Wf[0], acc);  \
    acc = MFMA16(A[0], Wf[1], acc);  \
    acc = MFMA16(A[1], Wf[0], acc);  \
    acc = MFMA16(A[1], Wf[1], acc);  \
    acc = MFMA16(A[0], Wf[2], acc);  \
    acc = MFMA16(A[2], Wf[0], acc);

// single-matrix GEMM (used for Q): wave w owns n-tile n=w.
// MFMA cluster at TOP priority (2); caller restores its own level after.
__device__ __forceinline__ void gemm_pass(const unsigned short* __restrict__ af,
                                          const unsigned short* __restrict__ wsplit,
                                          int w, int l, f32x4 acc[4]) {
    __builtin_amdgcn_s_setprio(2);
#pragma unroll
    for (int k = 0; k < 2; ++k) {
        bf16x8 wf[3];
#pragma unroll
        for (int p = 0; p < 3; ++p)
            wf[p] = *(const bf16x8*)(wsplit + (size_t)((((w * 2 + k) * 3 + p) * 512) + l * 8));
#pragma unroll
        for (int m = 0; m < 4; ++m) {
            bf16x8 a[3];
            read_frag(af, m * 2 + k, l, a);
            GEMM6(acc[m], a, wf);
        }
    }
}

// merged K+V GEMM: 8 independent accumulator chains, shared W-frags,
// one ds_read pair per sub-tile feeds two GEMM6 clusters.
__device__ __forceinline__ void gemm_pass2(const unsigned short* __restrict__ afK,
                                           const unsigned short* __restrict__ afV,
                                           const unsigned short* __restrict__ wsplit,
                                           int w, int l,
                                           f32x4 accK[4], f32x4 accV[4]) {
    __builtin_amdgcn_s_setprio(2);
#pragma unroll
    for (int k = 0; k < 2; ++k) {
        bf16x8 wf[3];
#pragma unroll
        for (int p = 0; p < 3; ++p)
            wf[p] = *(const bf16x8*)(wsplit + (size_t)((((w * 2 + k) * 3 + p) * 512) + l * 8));
#pragma unroll
        for (int m = 0; m < 4; ++m) {
            bf16x8 aK[3], aV[3];
            read_frag(afK, m * 2 + k, l, aK);
            read_frag(afV, m * 2 + k, l, aV);
            GEMM6(accK[m], aK, wf);
            GEMM6(accV[m], aV, wf);
        }
    }
}

__device__ __forceinline__ unsigned long long agg_ld(const unsigned long long* p) {
    return __hip_atomic_load(p, __ATOMIC_RELAXED, __HIP_MEMORY_SCOPE_AGENT);
}

// ---- fused kernel ----------------------------------------------------------
__global__ __launch_bounds__(THR, 4) void k_main(const float* __restrict__ Q,
                                                 const float* __restrict__ K,
                                                 const float* __restrict__ V,
                                                 const unsigned short* __restrict__ wsplit,
                                                 float* __restrict__ out,
                                                 unsigned long long* __restrict__ agg)
{
    __shared__ unsigned short afK[24 * SLOT];   // 24960 B each, 74880 total
    __shared__ unsigned short afV[24 * SLOT];
    __shared__ unsigned short afQ[24 * SLOT];

    // XCD-grouped: all 16 blocks of batch b land on XCD b%8 (i = m*32 + b,
    // 32 == 0 mod 8); predecessors (smaller m) have smaller linear id.
    const int i0 = blockIdx.x;
    const int b = i0 & 31, m = i0 >> 5;          // 16 blocks per batch
    const int t = threadIdx.x, w = t >> 6, l = t & 63;
    const int col = l & 15, g = l >> 4;
    const int fidx = w * 16 + col;

    // prologue: load chunk m
    float4 ldK[2], ldV[2], ldQ[2];
    {
        const size_t rb = ((size_t)b * cS + (size_t)m * CHUNK) * cD;
        load_mat((const float4*)(K + rb), t, ldK);
        load_mat((const float4*)(V + rb), t, ldV);
        load_mat((const float4*)(Q + rb), t, ldQ);
    }
    float carK = 0.f, carV = 0.f;   // prefix through previous own chunk (incl)

    for (int j = 0; j < ITERS; ++j) {
        const int c = j * BPB + m;

        // ---- prio 0: stage current chunk; issue next chunk's loads ----
        __syncthreads();                       // af free (prev iter reads done)
        write_mat(ldK, afK, t);
        write_mat(ldV, afV, t);
        write_mat(ldQ, afQ, t);
        if (j + 1 < ITERS) {
            const size_t rb = ((size_t)b * cS + (size_t)(c + BPB) * CHUNK) * cD;
            load_mat((const float4*)(K + rb), t, ldK);
            load_mat((const float4*)(V + rb), t, ldV);
            load_mat((const float4*)(Q + rb), t, ldQ);
        }
        __syncthreads();                       // af ready

        // ---- prio 2: K and V feature GEMMs (merged, 8 chains) ----
        f32x4 accK[4] = {};
        f32x4 accV[4] = {};
        gemm_pass2(afK, afV, wsplit, w, l, accK, accV);
        __builtin_amdgcn_s_setprio(1);         // stay elevated on serial chain

        // ---- prio 1: gate: accK := k_s, accV := k_s * v_f ----
#pragma unroll
        for (int mm = 0; mm < 4; ++mm)
#pragma unroll
            for (int r = 0; r < 4; ++r) {
                float kf = accK[mm][r];
                float ks = (kf > 0.5f) ? kf : 0.f;
                accK[mm][r] = ks;
                accV[mm][r] = ks * accV[mm][r];
            }

        // ---- prio 1: fast chunk totals (fixed xor tree) + publish ASAP ----
        float ktot = 0.f, kvtot = 0.f;
#pragma unroll
        for (int mm = 0; mm < 4; ++mm)
#pragma unroll
            for (int r = 0; r < 4; ++r) {
                ktot += accK[mm][r];
                kvtot += accV[mm][r];
            }
        ktot += __shfl_xor(ktot, 16);
        ktot += __shfl_xor(ktot, 32);
        kvtot += __shfl_xor(kvtot, 16);
        kvtot += __shfl_xor(kvtot, 32);
        if (g == 0) {
            unsigned long long u = ((unsigned long long)__float_as_uint(kvtot) << 32)
                                 | (unsigned long long)__float_as_uint(ktot + 1.0f);
            __hip_atomic_store(agg + (size_t)(b * NCH + c) * cF + fidx, u,
                               __ATOMIC_RELAXED, __HIP_MEMORY_SCOPE_AGENT);
        }

        // ---- prio 1: issue walk loads (<=4/lane, independent) ----
        const int lastc = (j == 0) ? -1 : (c - BPB);
        const int cc0 = c - 1 - g;
        const unsigned long long* base = agg + (size_t)b * NCH * cF + fidx;
        unsigned long long vv[4];
#pragma unroll
        for (int s2 = 0; s2 < 4; ++s2) {
            int cc = cc0 - 4 * s2;
            vv[s2] = (cc > lastc) ? agg_ld(base + (size_t)cc * cF) : 0ull;
        }

        // ---- prio 1: in-chunk inclusive cumsum (serial VALU chain) ----
        {
            float cK = 0.f, cV = 0.f;
#pragma unroll
            for (int mm = 0; mm < 4; ++mm) {
                f32x4 aK = accK[mm], aV = accV[mm];
                aK[1] += aK[0]; aK[2] += aK[1]; aK[3] += aK[2];
                aV[1] += aV[0]; aV[2] += aV[1]; aV[3] += aV[2];
                float tK = aK[3], tV = aV[3];
                float uK = __shfl_up(tK, 16), uV = __shfl_up(tV, 16);
                if (g >= 1) { tK += uK; tV += uV; }
                float xK = __shfl_up(tK, 32), xV = __shfl_up(tV, 32);
                if (g >= 2) { tK += xK; tV += xV; }
                float eK = tK - aK[3] + cK;
                float eV = tV - aV[3] + cV;
                aK[0] += eK; aK[1] += eK; aK[2] += eK; aK[3] += eK;
                aV[0] += eV; aV[1] += eV; aV[2] += eV; aV[3] += eV;
                accK[mm] = aK; accV[mm] = aV;
                cK += __shfl(tK, 48 + col);
                cV += __shfl(tV, 48 + col);
            }
        }

        // ---- prio 0: finish walk (spin must yield to other block) ----
        __builtin_amdgcn_s_setprio(0);
        {
            float dk = 0.f, dv = 0.f;
#pragma unroll
            for (int s2 = 0; s2 < 4; ++s2) {
                int cc = cc0 - 4 * s2;
                if (cc > lastc) {
                    unsigned long long v0 = vv[s2];
                    while ((unsigned)v0 == 0u) v0 = agg_ld(base + (size_t)cc * cF);
                    dk += __uint_as_float((unsigned)v0) - 1.0f;
                    dv += __uint_as_float((unsigned)(v0 >> 32));
                }
            }
            dk += __shfl_xor(dk, 16);
            dk += __shfl_xor(dk, 32);
            dv += __shfl_xor(dv, 16);
            dv += __shfl_xor(dv, 32);
            carK += dk;            // now = prefix through c-1
            carV += dv;
        }

        // ---- prio 1: attn in place: accV := attn (accK dead after) ----
        __builtin_amdgcn_s_setprio(1);
#pragma unroll
        for (int mm = 0; mm < 4; ++mm)
#pragma unroll
            for (int r = 0; r < 4; ++r) {
                float kc = accK[mm][r] + carK;
                float vc = accV[mm][r] + carV;
                accV[mm][r] = __fdividef(vc + EPS_, kc + EPS_);
            }
        carK += ktot;              // prefix through c (incl own chunk)
        carV += kvtot;

        // ---- prio 2: Q feature GEMM; prio 0: output store ----
        f32x4 accQ[4] = {};
        gemm_pass(afQ, wsplit, w, l, accQ);
        __builtin_amdgcn_s_setprio(0);

        const size_t obase = ((size_t)b * cS + (size_t)c * CHUNK) * cF;
#pragma unroll
        for (int mm = 0; mm < 4; ++mm)
#pragma unroll
            for (int r = 0; r < 4; ++r) {
                int s = mm * 16 + g * 4 + r;
                float qf = accQ[mm][r];
                float qs = (qf > 0.5f) ? qf : 0.f;
                out[obase + (size_t)s * cF + fidx] = qs * accV[mm][r];
            }
    }
}

// ---------------------------------------------------------------------------
extern "C" void kernel_launch(void* const* d_in, const int* in_sizes, int n_in,
                              void* d_out, int out_size, void* d_ws, size_t ws_size,
                              hipStream_t stream) {
    const float* q = (const float*)d_in[0];
    const float* k = (const float*)d_in[1];
    const float* v = (const float*)d_in[2];
    const float* w = (const float*)d_in[3];
    float* out = (float*)d_out;

    unsigned short* wsplit = (unsigned short*)d_ws;                       // 48 KiB
    unsigned long long* agg = (unsigned long long*)((char*)d_ws + 65536); // 4 MiB

    k_wsplit<<<32, 256, 0, stream>>>(w, wsplit, agg);  // also zeroes agg
    k_main<<<cB * BPB, THR, 0, stream>>>(q, k, v, wsplit, out, agg);
}